// Round 11
// baseline (191.691 us; speedup 1.0000x reference)
//
#include <hip/hip_runtime.h>

typedef _Float16 half8 __attribute__((ext_vector_type(8)));
typedef _Float16 half4 __attribute__((ext_vector_type(4)));
typedef float floatx4 __attribute__((ext_vector_type(4)));
typedef float floatx16 __attribute__((ext_vector_type(16)));

#define GLDS(gp, lp) __builtin_amdgcn_global_load_lds( \
    (const __attribute__((address_space(1))) void*)(gp), \
    (__attribute__((address_space(3))) void*)(lp), 16, 0, 0)

// ---------------------------------------------------------------- f32 -> f16 (5 tensors, one launch)
__global__ void cvt_f2h5(const float* __restrict__ s0, const float* __restrict__ s1,
                         const float* __restrict__ s2, const float* __restrict__ s3,
                         const float* __restrict__ s4,
                         _Float16* __restrict__ d0, _Float16* __restrict__ d1,
                         _Float16* __restrict__ d2, _Float16* __restrict__ d3,
                         _Float16* __restrict__ d4, int n8) {
  int i = blockIdx.x * 256 + threadIdx.x;
  if (i >= n8) return;
  const float* s; _Float16* d;
  switch (blockIdx.y) {
    case 0: s = s0; d = d0; break;
    case 1: s = s1; d = d1; break;
    case 2: s = s2; d = d2; break;
    case 3: s = s3; d = d3; break;
    default: s = s4; d = d4; break;
  }
  const float4* s4p = (const float4*)s;
  float4 a = s4p[2 * i], b = s4p[2 * i + 1];
  half8 h;
  h[0] = (_Float16)a.x; h[1] = (_Float16)a.y; h[2] = (_Float16)a.z; h[3] = (_Float16)a.w;
  h[4] = (_Float16)b.x; h[5] = (_Float16)b.y; h[6] = (_Float16)b.z; h[7] = (_Float16)b.w;
  *(half8*)(d + 8 * (size_t)i) = h;
}

// ---------------------------------------------------------------- 2048x2048 f16 transpose
__global__ __launch_bounds__(256) void transpose_k(const _Float16* __restrict__ src,
                                                   _Float16* __restrict__ dst) {
  __shared__ _Float16 t[64][72];
  const int r0 = blockIdx.y * 64, c0 = blockIdx.x * 64;
  const int tr = threadIdx.x >> 3, tc = (threadIdx.x & 7) * 8;
  #pragma unroll
  for (int p = 0; p < 2; ++p) {
    half8 v = *(const half8*)(src + (size_t)(r0 + p * 32 + tr) * 2048 + c0 + tc);
    *(half8*)&t[p * 32 + tr][tc] = v;
  }
  __syncthreads();
  #pragma unroll
  for (int p = 0; p < 2; ++p) {
    half8 v;
    #pragma unroll
    for (int j = 0; j < 8; ++j) v[j] = t[tc + j][p * 32 + tr];
    *(half8*)(dst + (size_t)(c0 + p * 32 + tr) * 2048 + r0 + tc) = v;
  }
}

// ---------------------------------------------------------------- fused QKV GEMM (round-8 verbatim, measured 60.2us)
// C[2048, 6144] = X[2048,2048] * W[6144,2048]^T. 256x192 tiles, grid 32x8 = 256 = 1/CU.
// 8 waves (2M x 4N); BK=64; A triple-, B double-buffered; counted vmcnt(4) steady state.
__global__ __launch_bounds__(512, 1) void gemm_qkv(const _Float16* __restrict__ A,
                                                   const _Float16* __restrict__ W,
                                                   _Float16* __restrict__ Cq) {
  extern __shared__ _Float16 lds[];
  _Float16* As = lds;                // [3][256*64]
  _Float16* Bs = lds + 3 * 16384;    // [2][192*64]

  const int tid = threadIdx.x, lane = tid & 63, wv = tid >> 6;
  const int fr = lane & 15, fg = lane >> 4;
  const int wm = wv >> 2, wn = wv & 3;
  const int bm = blockIdx.y * 256, bn = blockIdx.x * 192;
  const _Float16* Ab = A + (size_t)bm * 2048;
  const _Float16* Bb = W + (size_t)bn * 2048;

  const int srow = lane >> 3;                  // 0..7
  const int sgr = (lane & 7) ^ srow;           // pre-swizzled source granule

  auto stageA = [&](int t) {                   // 4 ops/wave, 256 rows
    _Float16* dst = As + (t % 3) * 16384;
    const size_t coff = (size_t)t * 64 + sgr * 8;
    #pragma unroll
    for (int i = 0; i < 4; ++i) {
      const int rb = wv * 32 + i * 8;
      GLDS(Ab + (size_t)(rb + srow) * 2048 + coff, dst + rb * 64);
    }
  };
  auto stageB = [&](int t) {                   // 3 ops/wave, 192 rows
    _Float16* dst = Bs + (t & 1) * 12288;
    const size_t coff = (size_t)t * 64 + sgr * 8;
    #pragma unroll
    for (int i = 0; i < 3; ++i) {
      const int rb = wv * 24 + i * 8;
      GLDS(Bb + (size_t)(rb + srow) * 2048 + coff, dst + rb * 64);
    }
  };

  const int arow = wm * 128 + fr;
  const int brow = wn * 48 + fr;
  const int sw = fr & 7;

  floatx4 acc[8][3] = {};

  stageA(0); stageB(0); stageA(1);
  asm volatile("s_waitcnt vmcnt(4)" ::: "memory");
  __builtin_amdgcn_s_barrier();

  for (int t = 0; t < 32; ++t) {
    const _Float16* Ac = As + (t % 3) * 16384;
    const _Float16* Bc = Bs + (t & 1) * 12288;
    #pragma unroll
    for (int p = 0; p < 4; ++p) {
      const int kh = p >> 1, qm = p & 1;
      const int sl = ((kh * 4 + fg) ^ sw) * 8;
      half8 af[4], bf[3];
      #pragma unroll
      for (int m = 0; m < 4; ++m)
        af[m] = *(const half8*)(Ac + (arow + qm * 64 + m * 16) * 64 + sl);
      #pragma unroll
      for (int n = 0; n < 3; ++n)
        bf[n] = *(const half8*)(Bc + (brow + n * 16) * 64 + sl);
      if (p == 0 && t + 1 < 32) stageB(t + 1);
      if (p == 2 && t + 2 < 32) stageA(t + 2);
      __builtin_amdgcn_s_barrier();
      asm volatile("s_waitcnt lgkmcnt(0)" ::: "memory");
      __builtin_amdgcn_sched_barrier(0);
      __builtin_amdgcn_s_setprio(1);
      #pragma unroll
      for (int m = 0; m < 4; ++m)
        #pragma unroll
        for (int n = 0; n < 3; ++n)
          acc[qm * 4 + m][n] =
              __builtin_amdgcn_mfma_f32_16x16x32_f16(af[m], bf[n], acc[qm * 4 + m][n], 0, 0, 0);
      __builtin_amdgcn_s_setprio(0);
      if (p == 3) {
        if (t < 30)       asm volatile("s_waitcnt vmcnt(4)" ::: "memory");
        else if (t == 30) asm volatile("s_waitcnt vmcnt(0)" ::: "memory");
      }
      __builtin_amdgcn_s_barrier();
    }
  }

  #pragma unroll
  for (int m = 0; m < 8; ++m)
    #pragma unroll
    for (int n = 0; n < 3; ++n)
      #pragma unroll
      for (int i = 0; i < 4; ++i) {
        const int row = bm + wm * 128 + m * 16 + fg * 4 + i;
        const int col = bn + wn * 48 + n * 16 + fr;       // 0..6143
        Cq[(size_t)(col >> 11) * 4194304 + (size_t)row * 2048 + (col & 2047)] =
            (_Float16)acc[m][n][i];
      }
}

// ---------------------------------------------------------------- RoPE (in-place on Q and K)
__global__ void rope_k(_Float16* __restrict__ Q, _Float16* __restrict__ K) {
  const int idx = blockIdx.x * 256 + threadIdx.x;
  const int s = idx >> 10;
  const int hd = idx & 1023;
  const int head = hd >> 6, d = hd & 63;
  const float freq = exp2f((float)d * -0.2076205059304601f);  // 10000^(-d/64)
  const float ang = (float)s * freq;
  float sn, c;
  __sincosf(ang, &sn, &c);
  const size_t base = (size_t)s * 2048 + head * 128 + d;
  float q1 = (float)Q[base], q2 = (float)Q[base + 64];
  Q[base]      = (_Float16)(q1 * c - q2 * sn);
  Q[base + 64] = (_Float16)(q2 * c + q1 * sn);
  float k1 = (float)K[base], k2 = (float)K[base + 64];
  K[base]      = (_Float16)(k1 * c - k2 * sn);
  K[base + 64] = (_Float16)(k2 * c + k1 * sn);
}

// ---------------------------------------------------------------- causal flash attention (32x32 MFMA)
// 768 blocks; unit (head, L) -> (g, kv-chunk); writes UNNORMALIZED partial O + sum-exp.
__global__ __launch_bounds__(256, 2) void attn_k(const _Float16* __restrict__ Qp,
                                                 const _Float16* __restrict__ Kp,
                                                 const _Float16* __restrict__ Vt,
                                                 _Float16* __restrict__ Po,
                                                 float* __restrict__ Pr) {
  extern __shared__ _Float16 smem[];
  _Float16* Ks = smem;                    // [2][64*128]
  _Float16* Vs = smem + 2 * 64 * 128;     // [2][128*64]
  _Float16* Pb = smem + 4 * 64 * 128;     // [4][32*40]

  const int tid = threadIdx.x, lane = tid & 63, wv = tid >> 6;
  const int l31 = lane & 31, hi = lane >> 5;
  const int wq = wv >> 1, wk = wv & 1;

  const int bid = (int)blockIdx.x;
  const int head = ((bid & 7) << 1) | ((bid >> 3) & 1);  // 2 heads per XCD
  const int L = bid >> 4;                                // 0..47
  int g, it0, itEnd;
  if (L < 16) { g = 16 + L; it0 = 0; itEnd = 16; }
  else {
    const int j = (L - 16) >> 1;
    if ((L & 1) == 0) { g = 15 - j; it0 = 0; itEnd = g + 1; }
    else             { g = 31 - j; it0 = 16; itEnd = g + 1; }
  }
  const size_t hoff = (size_t)head * 128;
  const int qw = g * 64 + wq * 32;
  _Float16* Pw = Pb + wv * (32 * 40);

  half8 qf[8];
  const _Float16 scl = (_Float16)0.08838834764831845f;
  #pragma unroll
  for (int ks = 0; ks < 8; ++ks) {
    half8 t = *(const half8*)(Qp + (size_t)(qw + l31) * 2048 + hoff + ks * 16 + hi * 8);
    #pragma unroll
    for (int j = 0; j < 8; ++j) t[j] = (_Float16)(t[j] * scl);
    qf[ks] = t;
  }

  auto stage = [&](int buf, int it) {
    const int kv0 = it * 64;
    #pragma unroll
    for (int i = 0; i < 4; ++i) {       // K: 4 rows per 1KB op
      const int rbase = wv * 16 + i * 4;
      const int row = rbase + (lane >> 4);
      const int gr = (lane & 15) ^ (row & 7);
      GLDS(Kp + (size_t)(kv0 + row) * 2048 + hoff + gr * 8,
           Ks + buf * 8192 + rbase * 128);
    }
    #pragma unroll
    for (int i = 0; i < 4; ++i) {       // V^T: 8 rows per 1KB op
      const int rbase = wv * 32 + i * 8;
      const int row = rbase + (lane >> 3);
      const int gr = (lane & 7) ^ (row & 7);
      GLDS(Vt + (size_t)(hoff + row) * 2048 + kv0 + gr * 8,
           Vs + buf * 8192 + rbase * 64);
    }
  };

  floatx16 o[4] = {};
  float rsum = 0.0f;

  stage(0, it0);
  __syncthreads();

  int buf = 0;
  for (int it = it0; it < itEnd; ++it) {
    if (it + 1 < itEnd) stage(buf ^ 1, it + 1);
    const _Float16* Kb = Ks + buf * 8192;
    const _Float16* Vb = Vs + buf * 8192;

    const int krow = wk * 32 + l31;
    const int ksw = l31 & 7;
    floatx16 S = {};
    __builtin_amdgcn_s_setprio(1);
    #pragma unroll
    for (int ks = 0; ks < 8; ++ks) {
      half8 a = *(const half8*)(Kb + krow * 128 + (((ks * 2 + hi) ^ ksw) * 8));
      S = __builtin_amdgcn_mfma_f32_32x32x16_f16(a, qf[ks], S, 0, 0, 0);
    }
    __builtin_amdgcn_s_setprio(0);

    if (it == g) {
      const int kv0 = it * 64;
      const int qa = qw + l31;
      #pragma unroll
      for (int r = 0; r < 16; ++r) {
        const int ka = kv0 + wk * 32 + (r & 3) + 8 * (r >> 2) + 4 * hi;
        if (ka > qa) S[r] = -1e30f;
      }
    }

    #pragma unroll
    for (int r4 = 0; r4 < 4; ++r4) {
      float p0 = __expf(S[4 * r4 + 0] - 8.0f);
      float p1 = __expf(S[4 * r4 + 1] - 8.0f);
      float p2 = __expf(S[4 * r4 + 2] - 8.0f);
      float p3 = __expf(S[4 * r4 + 3] - 8.0f);
      rsum += (p0 + p1) + (p2 + p3);
      half4 pk;
      pk[0] = (_Float16)p0; pk[1] = (_Float16)p1;
      pk[2] = (_Float16)p2; pk[3] = (_Float16)p3;
      *(half4*)(Pw + l31 * 40 + r4 * 8 + hi * 4) = pk;
    }

    half8 pa0 = *(const half8*)(Pw + l31 * 40 + hi * 8);
    half8 pa1 = *(const half8*)(Pw + l31 * 40 + 16 + hi * 8);

    __builtin_amdgcn_s_setprio(1);
    #pragma unroll
    for (int dt = 0; dt < 4; ++dt) {
      const int vrow = dt * 32 + l31;
      const int vsw = vrow & 7;
      half8 b0 = *(const half8*)(Vb + vrow * 64 + (((wk * 4 + hi) ^ vsw) * 8));
      half8 b1 = *(const half8*)(Vb + vrow * 64 + (((wk * 4 + 2 + hi) ^ vsw) * 8));
      o[dt] = __builtin_amdgcn_mfma_f32_32x32x16_f16(pa0, b0, o[dt], 0, 0, 0);
      o[dt] = __builtin_amdgcn_mfma_f32_32x32x16_f16(pa1, b1, o[dt], 0, 0, 0);
    }
    __builtin_amdgcn_s_setprio(0);

    __syncthreads();
    buf ^= 1;
  }

  float* Mo = (float*)smem;
  float* Mr = (float*)(smem + 16384);
  if (wk == 1) {
    #pragma unroll
    for (int dt = 0; dt < 4; ++dt)
      #pragma unroll
      for (int r = 0; r < 16; ++r)
        Mo[((wq * 4 + dt) * 16 + r) * 64 + lane] = o[dt][r];
    Mr[wq * 64 + lane] = rsum;
  }
  __syncthreads();
  if (wk == 0) {
    rsum += Mr[wq * 64 + lane];
    float rs = rsum;
    rs += __shfl_xor(rs, 32);
    if (hi == 0) Pr[(size_t)bid * 64 + wq * 32 + l31] = rs;
    #pragma unroll
    for (int dt = 0; dt < 4; ++dt)
      #pragma unroll
      for (int r = 0; r < 16; ++r) {
        const float w = o[dt][r] + Mo[((wq * 4 + dt) * 16 + r) * 64 + lane];
        const int ql = wq * 32 + (r & 3) + 8 * (r >> 2) + 4 * hi;
        Po[(size_t)bid * 8192 + ql * 128 + dt * 32 + l31] = (_Float16)w;
      }
  }
}

// ---------------------------------------------------------------- O-projection with fused chunk-merge
// out[2048,2048] f32 = merge(Po,Pr)[2048,2048] * Wo[2048,2048]^T. 128x128 tiles, 256 blocks.
// A-operand is produced in-LDS by a reg-staged merge: per K-step kt the 32 A-cols lie
// in ONE head (h=kt>>2, d0=(kt&3)*32); thread loads <=2 Po half8 partials + Pr sums,
// normalizes AFTER the MFMA cluster (T14 order), ds_writes swizzled. B via global_load_lds.
__global__ __launch_bounds__(256) void gemm_out(const _Float16* __restrict__ Po,
                                                const float* __restrict__ Pr,
                                                const _Float16* __restrict__ Wo,
                                                float* __restrict__ out) {
  __shared__ _Float16 As[2][128 * 32];
  __shared__ _Float16 Bs[2][128 * 32];
  const int tid = threadIdx.x, lane = tid & 63, wv = tid >> 6;
  const int fr = lane & 15, fg = lane >> 4;
  const int bm = blockIdx.y * 128, bn = blockIdx.x * 128;
  const _Float16* Bb = Wo + (size_t)bn * 2048;
  const int srow = lane >> 2;
  const int gsw = (lane & 3) ^ ((lane >> 3) & 3);
  const int asw = (fr >> 1) & 3;
  const int wm = (wv >> 1) * 64, wn = (wv & 1) * 64;
  // A merge-stage mapping: thread -> col-group (8 cols) x 2 rows (r0, r0+64)
  const int cg = tid & 3;
  const int r0 = tid >> 2;

  auto stageB = [&](int buf, int kt) {
    #pragma unroll
    for (int r = 0; r < 2; ++r) {
      int row = r * 64 + wv * 16 + srow;
      GLDS(Bb + (size_t)row * 2048 + kt * 32 + gsw * 8, &Bs[buf][(r * 64 + wv * 16) * 32]);
    }
  };

  auto loadA = [&](int kt, int pr, half8& a, half8& b, float& iv, bool& tw) {
    const int h = kt >> 2, dbase = (kt & 3) * 32;
    const int hb = ((h & 1) << 3) | (h >> 1);
    const int r = r0 + pr * 64;
    const int q = bm + r;
    const int g = q >> 6, ql = q & 63;
    tw = (g >= 16);
    const int L0 = tw ? (g - 16) : (16 + 2 * (15 - g));
    const int U0 = L0 * 16 + hb;
    a = *(const half8*)(Po + (size_t)U0 * 8192 + ql * 128 + dbase + cg * 8);
    float rs = Pr[(size_t)U0 * 64 + ql];
    if (tw) {
      const int U1 = (17 + 2 * (31 - g)) * 16 + hb;
      b = *(const half8*)(Po + (size_t)U1 * 8192 + ql * 128 + dbase + cg * 8);
      rs += Pr[(size_t)U1 * 64 + ql];
    }
    iv = 1.0f / rs;
  };
  auto writeA = [&](int buf, int pr, half8 a, half8 b, float iv, bool tw) {
    const int r = r0 + pr * 64;
    half8 o;
    #pragma unroll
    for (int j = 0; j < 8; ++j) {
      const float v = (float)a[j] + (tw ? (float)b[j] : 0.0f);
      o[j] = (_Float16)(v * iv);
    }
    *(half8*)&As[buf][r * 32 + ((cg ^ ((r >> 1) & 3)) * 8)] = o;
  };

  floatx4 acc[4][4] = {};
  half8 pa[2] = {}, pb[2] = {};
  float iv[2];
  bool tw[2];

  // prologue: stage kt=0 (B glds + A merge)
  stageB(0, 0);
  #pragma unroll
  for (int pr = 0; pr < 2; ++pr) loadA(0, pr, pa[pr], pb[pr], iv[pr], tw[pr]);
  #pragma unroll
  for (int pr = 0; pr < 2; ++pr) writeA(0, pr, pa[pr], pb[pr], iv[pr], tw[pr]);
  __syncthreads();

  for (int kt = 0; kt < 64; ++kt) {
    const int cur = kt & 1;
    if (kt < 63) {
      stageB(cur ^ 1, kt + 1);
      #pragma unroll
      for (int pr = 0; pr < 2; ++pr) loadA(kt + 1, pr, pa[pr], pb[pr], iv[pr], tw[pr]);
    }
    half8 af[4], bf[4];
    #pragma unroll
    for (int m = 0; m < 4; ++m)
      af[m] = *(const half8*)&As[cur][(wm + m * 16 + fr) * 32 + ((fg ^ asw) * 8)];
    #pragma unroll
    for (int n = 0; n < 4; ++n)
      bf[n] = *(const half8*)&Bs[cur][(wn + n * 16 + fr) * 32 + ((fg ^ asw) * 8)];
    #pragma unroll
    for (int m = 0; m < 4; ++m)
      #pragma unroll
      for (int n = 0; n < 4; ++n)
        acc[m][n] = __builtin_amdgcn_mfma_f32_16x16x32_f16(af[m], bf[n], acc[m][n], 0, 0, 0);
    if (kt < 63) {
      #pragma unroll
      for (int pr = 0; pr < 2; ++pr) writeA(cur ^ 1, pr, pa[pr], pb[pr], iv[pr], tw[pr]);
    }
    __syncthreads();
  }

  #pragma unroll
  for (int m = 0; m < 4; ++m)
    #pragma unroll
    for (int n = 0; n < 4; ++n)
      #pragma unroll
      for (int i = 0; i < 4; ++i) {
        const int row = bm + wm + m * 16 + fg * 4 + i;
        const int col = bn + wn + n * 16 + fr;
        out[(size_t)row * 2048 + col] = acc[m][n][i];
      }
}

// ---------------------------------------------------------------- launch
extern "C" void kernel_launch(void* const* d_in, const int* in_sizes, int n_in,
                              void* d_out, int out_size, void* d_ws, size_t ws_size,
                              hipStream_t stream) {
  (void)in_sizes; (void)n_in; (void)out_size; (void)ws_size;
  const float* X  = (const float*)d_in[0];
  const float* Wq = (const float*)d_in[1];
  const float* Wk = (const float*)d_in[2];
  const float* Wv = (const float*)d_in[3];
  const float* Wo = (const float*)d_in[4];
  float* out = (float*)d_out;

  const size_t SZ = 2048ull * 2048ull;
  _Float16* ws  = (_Float16*)d_ws;
  _Float16* Xh  = ws + 0 * SZ;
  _Float16* Wqh = ws + 1 * SZ;   // Wq|Wk|Wv contiguous = one 6144x2048 matrix
  _Float16* Wkh = ws + 2 * SZ;
  _Float16* Wvh = ws + 3 * SZ;
  _Float16* Woh = ws + 4 * SZ;
  _Float16* Qp  = ws + 5 * SZ;   // Q|K|V contiguous = C of the fused GEMM
  _Float16* Kp  = ws + 6 * SZ;
  _Float16* Vp  = ws + 7 * SZ;
  _Float16* Vtg = Wqh;            // dead after QKV GEMM -> V^T
  _Float16* Po  = Wkh;            // dead after QKV GEMM -> attn partials (spans Wkh+Wvh)
  float*    Pr  = (float*)Vp;     // dead after transpose -> chunk sum-exp

  const int n8 = (int)(SZ / 8);
  dim3 blk(256);

  cvt_f2h5<<<dim3(n8 / 256, 5), blk, 0, stream>>>(X, Wq, Wk, Wv, Wo,
                                                  Xh, Wqh, Wkh, Wvh, Woh, n8);

  // fused QKV projection: 256 blocks (1/CU), counted-vmcnt pipeline (round-8 best)
  gemm_qkv<<<dim3(32, 8), dim3(512), 147456, stream>>>(Xh, Wqh, Qp);
  rope_k<<<(2048 * 1024) / 256, blk, 0, stream>>>(Qp, Kp);
  transpose_k<<<dim3(32, 32), blk, 0, stream>>>(Vp, Vtg);

  const size_t attn_lds = (4 * 64 * 128 + 4 * 32 * 40) * sizeof(_Float16);  // 75776 B
  attn_k<<<768, blk, attn_lds, stream>>>(Qp, Kp, Vtg, Po, Pr);

  // O-projection with fused chunk-merge (reads Po/Pr directly; attn_merge eliminated)
  gemm_out<<<dim3(16, 16), blk, 0, stream>>>(Po, Pr, Woh, out);
}

// Round 12
// 191.355 us; speedup vs baseline: 1.0018x; 1.0018x over previous
//
#include <hip/hip_runtime.h>

typedef _Float16 half8 __attribute__((ext_vector_type(8)));
typedef _Float16 half4 __attribute__((ext_vector_type(4)));
typedef float floatx4 __attribute__((ext_vector_type(4)));
typedef float floatx16 __attribute__((ext_vector_type(16)));

#define GLDS(gp, lp) __builtin_amdgcn_global_load_lds( \
    (const __attribute__((address_space(1))) void*)(gp), \
    (__attribute__((address_space(3))) void*)(lp), 16, 0, 0)

// ---------------------------------------------------------------- f32 -> f16 (5 tensors, one launch)
__global__ void cvt_f2h5(const float* __restrict__ s0, const float* __restrict__ s1,
                         const float* __restrict__ s2, const float* __restrict__ s3,
                         const float* __restrict__ s4,
                         _Float16* __restrict__ d0, _Float16* __restrict__ d1,
                         _Float16* __restrict__ d2, _Float16* __restrict__ d3,
                         _Float16* __restrict__ d4, int n8) {
  int i = blockIdx.x * 256 + threadIdx.x;
  if (i >= n8) return;
  const float* s; _Float16* d;
  switch (blockIdx.y) {
    case 0: s = s0; d = d0; break;
    case 1: s = s1; d = d1; break;
    case 2: s = s2; d = d2; break;
    case 3: s = s3; d = d3; break;
    default: s = s4; d = d4; break;
  }
  const float4* s4p = (const float4*)s;
  float4 a = s4p[2 * i], b = s4p[2 * i + 1];
  half8 h;
  h[0] = (_Float16)a.x; h[1] = (_Float16)a.y; h[2] = (_Float16)a.z; h[3] = (_Float16)a.w;
  h[4] = (_Float16)b.x; h[5] = (_Float16)b.y; h[6] = (_Float16)b.z; h[7] = (_Float16)b.w;
  *(half8*)(d + 8 * (size_t)i) = h;
}

// ---------------------------------------------------------------- 2048x2048 f16 transpose
__global__ __launch_bounds__(256) void transpose_k(const _Float16* __restrict__ src,
                                                   _Float16* __restrict__ dst) {
  __shared__ _Float16 t[64][72];
  const int r0 = blockIdx.y * 64, c0 = blockIdx.x * 64;
  const int tr = threadIdx.x >> 3, tc = (threadIdx.x & 7) * 8;
  #pragma unroll
  for (int p = 0; p < 2; ++p) {
    half8 v = *(const half8*)(src + (size_t)(r0 + p * 32 + tr) * 2048 + c0 + tc);
    *(half8*)&t[p * 32 + tr][tc] = v;
  }
  __syncthreads();
  #pragma unroll
  for (int p = 0; p < 2; ++p) {
    half8 v;
    #pragma unroll
    for (int j = 0; j < 8; ++j) v[j] = t[tc + j][p * 32 + tr];
    *(half8*)(dst + (size_t)(c0 + p * 32 + tr) * 2048 + r0 + tc) = v;
  }
}

// ---------------------------------------------------------------- fused QKV GEMM (round-8 verbatim, measured 60.2us)
// C[2048, 6144] = X[2048,2048] * W[6144,2048]^T. 256x192 tiles, grid 32x8 = 256 = 1/CU.
// 8 waves (2M x 4N); BK=64; A triple-, B double-buffered; counted vmcnt(4) steady state.
__global__ __launch_bounds__(512, 1) void gemm_qkv(const _Float16* __restrict__ A,
                                                   const _Float16* __restrict__ W,
                                                   _Float16* __restrict__ Cq) {
  extern __shared__ _Float16 lds[];
  _Float16* As = lds;                // [3][256*64]
  _Float16* Bs = lds + 3 * 16384;    // [2][192*64]

  const int tid = threadIdx.x, lane = tid & 63, wv = tid >> 6;
  const int fr = lane & 15, fg = lane >> 4;
  const int wm = wv >> 2, wn = wv & 3;
  const int bm = blockIdx.y * 256, bn = blockIdx.x * 192;
  const _Float16* Ab = A + (size_t)bm * 2048;
  const _Float16* Bb = W + (size_t)bn * 2048;

  const int srow = lane >> 3;                  // 0..7
  const int sgr = (lane & 7) ^ srow;           // pre-swizzled source granule

  auto stageA = [&](int t) {                   // 4 ops/wave, 256 rows
    _Float16* dst = As + (t % 3) * 16384;
    const size_t coff = (size_t)t * 64 + sgr * 8;
    #pragma unroll
    for (int i = 0; i < 4; ++i) {
      const int rb = wv * 32 + i * 8;
      GLDS(Ab + (size_t)(rb + srow) * 2048 + coff, dst + rb * 64);
    }
  };
  auto stageB = [&](int t) {                   // 3 ops/wave, 192 rows
    _Float16* dst = Bs + (t & 1) * 12288;
    const size_t coff = (size_t)t * 64 + sgr * 8;
    #pragma unroll
    for (int i = 0; i < 3; ++i) {
      const int rb = wv * 24 + i * 8;
      GLDS(Bb + (size_t)(rb + srow) * 2048 + coff, dst + rb * 64);
    }
  };

  const int arow = wm * 128 + fr;
  const int brow = wn * 48 + fr;
  const int sw = fr & 7;

  floatx4 acc[8][3] = {};

  stageA(0); stageB(0); stageA(1);
  asm volatile("s_waitcnt vmcnt(4)" ::: "memory");
  __builtin_amdgcn_s_barrier();

  for (int t = 0; t < 32; ++t) {
    const _Float16* Ac = As + (t % 3) * 16384;
    const _Float16* Bc = Bs + (t & 1) * 12288;
    #pragma unroll
    for (int p = 0; p < 4; ++p) {
      const int kh = p >> 1, qm = p & 1;
      const int sl = ((kh * 4 + fg) ^ sw) * 8;
      half8 af[4], bf[3];
      #pragma unroll
      for (int m = 0; m < 4; ++m)
        af[m] = *(const half8*)(Ac + (arow + qm * 64 + m * 16) * 64 + sl);
      #pragma unroll
      for (int n = 0; n < 3; ++n)
        bf[n] = *(const half8*)(Bc + (brow + n * 16) * 64 + sl);
      if (p == 0 && t + 1 < 32) stageB(t + 1);
      if (p == 2 && t + 2 < 32) stageA(t + 2);
      __builtin_amdgcn_s_barrier();
      asm volatile("s_waitcnt lgkmcnt(0)" ::: "memory");
      __builtin_amdgcn_sched_barrier(0);
      __builtin_amdgcn_s_setprio(1);
      #pragma unroll
      for (int m = 0; m < 4; ++m)
        #pragma unroll
        for (int n = 0; n < 3; ++n)
          acc[qm * 4 + m][n] =
              __builtin_amdgcn_mfma_f32_16x16x32_f16(af[m], bf[n], acc[qm * 4 + m][n], 0, 0, 0);
      __builtin_amdgcn_s_setprio(0);
      if (p == 3) {
        if (t < 30)       asm volatile("s_waitcnt vmcnt(4)" ::: "memory");
        else if (t == 30) asm volatile("s_waitcnt vmcnt(0)" ::: "memory");
      }
      __builtin_amdgcn_s_barrier();
    }
  }

  #pragma unroll
  for (int m = 0; m < 8; ++m)
    #pragma unroll
    for (int n = 0; n < 3; ++n)
      #pragma unroll
      for (int i = 0; i < 4; ++i) {
        const int row = bm + wm * 128 + m * 16 + fg * 4 + i;
        const int col = bn + wn * 48 + n * 16 + fr;       // 0..6143
        Cq[(size_t)(col >> 11) * 4194304 + (size_t)row * 2048 + (col & 2047)] =
            (_Float16)acc[m][n][i];
      }
}

// ---------------------------------------------------------------- RoPE (in-place on Q and K)
__global__ void rope_k(_Float16* __restrict__ Q, _Float16* __restrict__ K) {
  const int idx = blockIdx.x * 256 + threadIdx.x;
  const int s = idx >> 10;
  const int hd = idx & 1023;
  const int head = hd >> 6, d = hd & 63;
  const float freq = exp2f((float)d * -0.2076205059304601f);  // 10000^(-d/64)
  const float ang = (float)s * freq;
  float sn, c;
  __sincosf(ang, &sn, &c);
  const size_t base = (size_t)s * 2048 + head * 128 + d;
  float q1 = (float)Q[base], q2 = (float)Q[base + 64];
  Q[base]      = (_Float16)(q1 * c - q2 * sn);
  Q[base + 64] = (_Float16)(q2 * c + q1 * sn);
  float k1 = (float)K[base], k2 = (float)K[base + 64];
  K[base]      = (_Float16)(k1 * c - k2 * sn);
  K[base + 64] = (_Float16)(k2 * c + k1 * sn);
}

// ---------------------------------------------------------------- causal flash attention (32x32 MFMA)
// 768 blocks; unit (head, L) -> (g, kv-chunk); writes UNNORMALIZED partial O + sum-exp.
__global__ __launch_bounds__(256, 2) void attn_k(const _Float16* __restrict__ Qp,
                                                 const _Float16* __restrict__ Kp,
                                                 const _Float16* __restrict__ Vt,
                                                 _Float16* __restrict__ Po,
                                                 float* __restrict__ Pr) {
  extern __shared__ _Float16 smem[];
  _Float16* Ks = smem;                    // [2][64*128]
  _Float16* Vs = smem + 2 * 64 * 128;     // [2][128*64]
  _Float16* Pb = smem + 4 * 64 * 128;     // [4][32*40]

  const int tid = threadIdx.x, lane = tid & 63, wv = tid >> 6;
  const int l31 = lane & 31, hi = lane >> 5;
  const int wq = wv >> 1, wk = wv & 1;

  const int bid = (int)blockIdx.x;
  const int head = ((bid & 7) << 1) | ((bid >> 3) & 1);  // 2 heads per XCD
  const int L = bid >> 4;                                // 0..47
  int g, it0, itEnd;
  if (L < 16) { g = 16 + L; it0 = 0; itEnd = 16; }
  else {
    const int j = (L - 16) >> 1;
    if ((L & 1) == 0) { g = 15 - j; it0 = 0; itEnd = g + 1; }
    else             { g = 31 - j; it0 = 16; itEnd = g + 1; }
  }
  const size_t hoff = (size_t)head * 128;
  const int qw = g * 64 + wq * 32;
  _Float16* Pw = Pb + wv * (32 * 40);

  half8 qf[8];
  const _Float16 scl = (_Float16)0.08838834764831845f;
  #pragma unroll
  for (int ks = 0; ks < 8; ++ks) {
    half8 t = *(const half8*)(Qp + (size_t)(qw + l31) * 2048 + hoff + ks * 16 + hi * 8);
    #pragma unroll
    for (int j = 0; j < 8; ++j) t[j] = (_Float16)(t[j] * scl);
    qf[ks] = t;
  }

  auto stage = [&](int buf, int it) {
    const int kv0 = it * 64;
    #pragma unroll
    for (int i = 0; i < 4; ++i) {       // K: 4 rows per 1KB op
      const int rbase = wv * 16 + i * 4;
      const int row = rbase + (lane >> 4);
      const int gr = (lane & 15) ^ (row & 7);
      GLDS(Kp + (size_t)(kv0 + row) * 2048 + hoff + gr * 8,
           Ks + buf * 8192 + rbase * 128);
    }
    #pragma unroll
    for (int i = 0; i < 4; ++i) {       // V^T: 8 rows per 1KB op
      const int rbase = wv * 32 + i * 8;
      const int row = rbase + (lane >> 3);
      const int gr = (lane & 7) ^ (row & 7);
      GLDS(Vt + (size_t)(hoff + row) * 2048 + kv0 + gr * 8,
           Vs + buf * 8192 + rbase * 64);
    }
  };

  floatx16 o[4] = {};
  float rsum = 0.0f;

  stage(0, it0);
  __syncthreads();

  int buf = 0;
  for (int it = it0; it < itEnd; ++it) {
    if (it + 1 < itEnd) stage(buf ^ 1, it + 1);
    const _Float16* Kb = Ks + buf * 8192;
    const _Float16* Vb = Vs + buf * 8192;

    const int krow = wk * 32 + l31;
    const int ksw = l31 & 7;
    floatx16 S = {};
    __builtin_amdgcn_s_setprio(1);
    #pragma unroll
    for (int ks = 0; ks < 8; ++ks) {
      half8 a = *(const half8*)(Kb + krow * 128 + (((ks * 2 + hi) ^ ksw) * 8));
      S = __builtin_amdgcn_mfma_f32_32x32x16_f16(a, qf[ks], S, 0, 0, 0);
    }
    __builtin_amdgcn_s_setprio(0);

    if (it == g) {
      const int kv0 = it * 64;
      const int qa = qw + l31;
      #pragma unroll
      for (int r = 0; r < 16; ++r) {
        const int ka = kv0 + wk * 32 + (r & 3) + 8 * (r >> 2) + 4 * hi;
        if (ka > qa) S[r] = -1e30f;
      }
    }

    #pragma unroll
    for (int r4 = 0; r4 < 4; ++r4) {
      float p0 = __expf(S[4 * r4 + 0] - 8.0f);
      float p1 = __expf(S[4 * r4 + 1] - 8.0f);
      float p2 = __expf(S[4 * r4 + 2] - 8.0f);
      float p3 = __expf(S[4 * r4 + 3] - 8.0f);
      rsum += (p0 + p1) + (p2 + p3);
      half4 pk;
      pk[0] = (_Float16)p0; pk[1] = (_Float16)p1;
      pk[2] = (_Float16)p2; pk[3] = (_Float16)p3;
      *(half4*)(Pw + l31 * 40 + r4 * 8 + hi * 4) = pk;
    }

    half8 pa0 = *(const half8*)(Pw + l31 * 40 + hi * 8);
    half8 pa1 = *(const half8*)(Pw + l31 * 40 + 16 + hi * 8);

    __builtin_amdgcn_s_setprio(1);
    #pragma unroll
    for (int dt = 0; dt < 4; ++dt) {
      const int vrow = dt * 32 + l31;
      const int vsw = vrow & 7;
      half8 b0 = *(const half8*)(Vb + vrow * 64 + (((wk * 4 + hi) ^ vsw) * 8));
      half8 b1 = *(const half8*)(Vb + vrow * 64 + (((wk * 4 + 2 + hi) ^ vsw) * 8));
      o[dt] = __builtin_amdgcn_mfma_f32_32x32x16_f16(pa0, b0, o[dt], 0, 0, 0);
      o[dt] = __builtin_amdgcn_mfma_f32_32x32x16_f16(pa1, b1, o[dt], 0, 0, 0);
    }
    __builtin_amdgcn_s_setprio(0);

    __syncthreads();
    buf ^= 1;
  }

  float* Mo = (float*)smem;
  float* Mr = (float*)(smem + 16384);
  if (wk == 1) {
    #pragma unroll
    for (int dt = 0; dt < 4; ++dt)
      #pragma unroll
      for (int r = 0; r < 16; ++r)
        Mo[((wq * 4 + dt) * 16 + r) * 64 + lane] = o[dt][r];
    Mr[wq * 64 + lane] = rsum;
  }
  __syncthreads();
  if (wk == 0) {
    rsum += Mr[wq * 64 + lane];
    float rs = rsum;
    rs += __shfl_xor(rs, 32);
    if (hi == 0) Pr[(size_t)bid * 64 + wq * 32 + l31] = rs;
    #pragma unroll
    for (int dt = 0; dt < 4; ++dt)
      #pragma unroll
      for (int r = 0; r < 16; ++r) {
        const float w = o[dt][r] + Mo[((wq * 4 + dt) * 16 + r) * 64 + lane];
        const int ql = wq * 32 + (r & 3) + 8 * (r >> 2) + 4 * hi;
        Po[(size_t)bid * 8192 + ql * 128 + dt * 32 + l31] = (_Float16)w;
      }
  }
}

// ---------------------------------------------------------------- O-projection with fused chunk-merge
// out[2048,2048] f32 = merge(Po,Pr)[2048,2048] * Wo[2048,2048]^T. 128x128 tiles, 256 blocks.
// A-operand is produced in-LDS by a reg-staged merge: per K-step kt the 32 A-cols lie
// in ONE head (h=kt>>2, d0=(kt&3)*32); thread loads <=2 Po half8 partials + Pr sums,
// normalizes AFTER the MFMA cluster (T14 order), ds_writes swizzled. B via global_load_lds.
__global__ __launch_bounds__(256) void gemm_out(const _Float16* __restrict__ Po,
                                                const float* __restrict__ Pr,
                                                const _Float16* __restrict__ Wo,
                                                float* __restrict__ out) {
  __shared__ _Float16 As[2][128 * 32];
  __shared__ _Float16 Bs[2][128 * 32];
  const int tid = threadIdx.x, lane = tid & 63, wv = tid >> 6;
  const int fr = lane & 15, fg = lane >> 4;
  const int bm = blockIdx.y * 128, bn = blockIdx.x * 128;
  const _Float16* Bb = Wo + (size_t)bn * 2048;
  const int srow = lane >> 2;
  const int gsw = (lane & 3) ^ ((lane >> 3) & 3);
  const int asw = (fr >> 1) & 3;
  const int wm = (wv >> 1) * 64, wn = (wv & 1) * 64;
  // A merge-stage mapping: thread -> col-group (8 cols) x 2 rows (r0, r0+64)
  const int cg = tid & 3;
  const int r0 = tid >> 2;

  auto stageB = [&](int buf, int kt) {
    #pragma unroll
    for (int r = 0; r < 2; ++r) {
      int row = r * 64 + wv * 16 + srow;
      GLDS(Bb + (size_t)row * 2048 + kt * 32 + gsw * 8, &Bs[buf][(r * 64 + wv * 16) * 32]);
    }
  };

  auto loadA = [&](int kt, int pr, half8& a, half8& b, float& iv, bool& tw) {
    const int h = kt >> 2, dbase = (kt & 3) * 32;
    const int hb = ((h & 1) << 3) | (h >> 1);
    const int r = r0 + pr * 64;
    const int q = bm + r;
    const int g = q >> 6, ql = q & 63;
    tw = (g >= 16);
    const int L0 = tw ? (g - 16) : (16 + 2 * (15 - g));
    const int U0 = L0 * 16 + hb;
    a = *(const half8*)(Po + (size_t)U0 * 8192 + ql * 128 + dbase + cg * 8);
    float rs = Pr[(size_t)U0 * 64 + ql];
    if (tw) {
      const int U1 = (17 + 2 * (31 - g)) * 16 + hb;
      b = *(const half8*)(Po + (size_t)U1 * 8192 + ql * 128 + dbase + cg * 8);
      rs += Pr[(size_t)U1 * 64 + ql];
    }
    iv = 1.0f / rs;
  };
  auto writeA = [&](int buf, int pr, half8 a, half8 b, float iv, bool tw) {
    const int r = r0 + pr * 64;
    half8 o;
    #pragma unroll
    for (int j = 0; j < 8; ++j) {
      const float v = (float)a[j] + (tw ? (float)b[j] : 0.0f);
      o[j] = (_Float16)(v * iv);
    }
    *(half8*)&As[buf][r * 32 + ((cg ^ ((r >> 1) & 3)) * 8)] = o;
  };

  floatx4 acc[4][4] = {};
  half8 pa[2] = {}, pb[2] = {};
  float iv[2];
  bool tw[2];

  // prologue: stage kt=0 (B glds + A merge)
  stageB(0, 0);
  #pragma unroll
  for (int pr = 0; pr < 2; ++pr) loadA(0, pr, pa[pr], pb[pr], iv[pr], tw[pr]);
  #pragma unroll
  for (int pr = 0; pr < 2; ++pr) writeA(0, pr, pa[pr], pb[pr], iv[pr], tw[pr]);
  __syncthreads();

  for (int kt = 0; kt < 64; ++kt) {
    const int cur = kt & 1;
    if (kt < 63) {
      stageB(cur ^ 1, kt + 1);
      #pragma unroll
      for (int pr = 0; pr < 2; ++pr) loadA(kt + 1, pr, pa[pr], pb[pr], iv[pr], tw[pr]);
    }
    half8 af[4], bf[4];
    #pragma unroll
    for (int m = 0; m < 4; ++m)
      af[m] = *(const half8*)&As[cur][(wm + m * 16 + fr) * 32 + ((fg ^ asw) * 8)];
    #pragma unroll
    for (int n = 0; n < 4; ++n)
      bf[n] = *(const half8*)&Bs[cur][(wn + n * 16 + fr) * 32 + ((fg ^ asw) * 8)];
    #pragma unroll
    for (int m = 0; m < 4; ++m)
      #pragma unroll
      for (int n = 0; n < 4; ++n)
        acc[m][n] = __builtin_amdgcn_mfma_f32_16x16x32_f16(af[m], bf[n], acc[m][n], 0, 0, 0);
    if (kt < 63) {
      #pragma unroll
      for (int pr = 0; pr < 2; ++pr) writeA(cur ^ 1, pr, pa[pr], pb[pr], iv[pr], tw[pr]);
    }
    __syncthreads();
  }

  #pragma unroll
  for (int m = 0; m < 4; ++m)
    #pragma unroll
    for (int n = 0; n < 4; ++n)
      #pragma unroll
      for (int i = 0; i < 4; ++i) {
        const int row = bm + wm + m * 16 + fg * 4 + i;
        const int col = bn + wn + n * 16 + fr;
        out[(size_t)row * 2048 + col] = acc[m][n][i];
      }
}

// ---------------------------------------------------------------- launch
extern "C" void kernel_launch(void* const* d_in, const int* in_sizes, int n_in,
                              void* d_out, int out_size, void* d_ws, size_t ws_size,
                              hipStream_t stream) {
  (void)in_sizes; (void)n_in; (void)out_size; (void)ws_size;
  const float* X  = (const float*)d_in[0];
  const float* Wq = (const float*)d_in[1];
  const float* Wk = (const float*)d_in[2];
  const float* Wv = (const float*)d_in[3];
  const float* Wo = (const float*)d_in[4];
  float* out = (float*)d_out;

  const size_t SZ = 2048ull * 2048ull;
  _Float16* ws  = (_Float16*)d_ws;
  _Float16* Xh  = ws + 0 * SZ;
  _Float16* Wqh = ws + 1 * SZ;   // Wq|Wk|Wv contiguous = one 6144x2048 matrix
  _Float16* Wkh = ws + 2 * SZ;
  _Float16* Wvh = ws + 3 * SZ;
  _Float16* Woh = ws + 4 * SZ;
  _Float16* Qp  = ws + 5 * SZ;   // Q|K|V contiguous = C of the fused GEMM
  _Float16* Kp  = ws + 6 * SZ;
  _Float16* Vp  = ws + 7 * SZ;
  _Float16* Vtg = Wqh;            // dead after QKV GEMM -> V^T
  _Float16* Po  = Wkh;            // dead after QKV GEMM -> attn partials (spans Wkh+Wvh)
  float*    Pr  = (float*)Vp;     // dead after transpose -> chunk sum-exp

  const int n8 = (int)(SZ / 8);
  dim3 blk(256);

  cvt_f2h5<<<dim3(n8 / 256, 5), blk, 0, stream>>>(X, Wq, Wk, Wv, Wo,
                                                  Xh, Wqh, Wkh, Wvh, Woh, n8);

  // fused QKV projection: 256 blocks (1/CU), counted-vmcnt pipeline (round-8 best)
  gemm_qkv<<<dim3(32, 8), dim3(512), 147456, stream>>>(Xh, Wqh, Qp);
  rope_k<<<(2048 * 1024) / 256, blk, 0, stream>>>(Qp, Kp);
  transpose_k<<<dim3(32, 32), blk, 0, stream>>>(Vp, Vtg);

  const size_t attn_lds = (4 * 64 * 128 + 4 * 32 * 40) * sizeof(_Float16);  // 75776 B
  attn_k<<<768, blk, attn_lds, stream>>>(Qp, Kp, Vtg, Po, Pr);

  // O-projection with fused chunk-merge (reads Po/Pr directly; attn_merge eliminated)
  gemm_out<<<dim3(16, 16), blk, 0, stream>>>(Po, Pr, Woh, out);
}

// Round 13
// 164.164 us; speedup vs baseline: 1.1677x; 1.1656x over previous
//
#include <hip/hip_runtime.h>

typedef _Float16 half8 __attribute__((ext_vector_type(8)));
typedef _Float16 half4 __attribute__((ext_vector_type(4)));
typedef float floatx4 __attribute__((ext_vector_type(4)));
typedef float floatx16 __attribute__((ext_vector_type(16)));

#define GLDS(gp, lp) __builtin_amdgcn_global_load_lds( \
    (const __attribute__((address_space(1))) void*)(gp), \
    (__attribute__((address_space(3))) void*)(lp), 16, 0, 0)

// ---------------------------------------------------------------- f32 -> f16 (5 tensors, one launch)
__global__ void cvt_f2h5(const float* __restrict__ s0, const float* __restrict__ s1,
                         const float* __restrict__ s2, const float* __restrict__ s3,
                         const float* __restrict__ s4,
                         _Float16* __restrict__ d0, _Float16* __restrict__ d1,
                         _Float16* __restrict__ d2, _Float16* __restrict__ d3,
                         _Float16* __restrict__ d4, int n8) {
  int i = blockIdx.x * 256 + threadIdx.x;
  if (i >= n8) return;
  const float* s; _Float16* d;
  switch (blockIdx.y) {
    case 0: s = s0; d = d0; break;
    case 1: s = s1; d = d1; break;
    case 2: s = s2; d = d2; break;
    case 3: s = s3; d = d3; break;
    default: s = s4; d = d4; break;
  }
  const float4* s4p = (const float4*)s;
  float4 a = s4p[2 * i], b = s4p[2 * i + 1];
  half8 h;
  h[0] = (_Float16)a.x; h[1] = (_Float16)a.y; h[2] = (_Float16)a.z; h[3] = (_Float16)a.w;
  h[4] = (_Float16)b.x; h[5] = (_Float16)b.y; h[6] = (_Float16)b.z; h[7] = (_Float16)b.w;
  *(half8*)(d + 8 * (size_t)i) = h;
}

// ---------------------------------------------------------------- fused RoPE + V-transpose (one launch)
// blocks [0,8192): RoPE in-place on Q,K. blocks [8192,9216): transpose V -> Vt.
__global__ __launch_bounds__(256) void rope_tr(_Float16* __restrict__ Q,
                                               _Float16* __restrict__ K,
                                               const _Float16* __restrict__ V,
                                               _Float16* __restrict__ Vt) {
  __shared__ _Float16 t[64][72];
  const int bid = (int)blockIdx.x;
  if (bid < 8192) {
    const int idx = bid * 256 + threadIdx.x;
    const int s = idx >> 10;
    const int hd = idx & 1023;
    const int head = hd >> 6, d = hd & 63;
    const float freq = exp2f((float)d * -0.2076205059304601f);  // 10000^(-d/64)
    const float ang = (float)s * freq;
    float sn, c;
    __sincosf(ang, &sn, &c);
    const size_t base = (size_t)s * 2048 + head * 128 + d;
    float q1 = (float)Q[base], q2 = (float)Q[base + 64];
    Q[base]      = (_Float16)(q1 * c - q2 * sn);
    Q[base + 64] = (_Float16)(q2 * c + q1 * sn);
    float k1 = (float)K[base], k2 = (float)K[base + 64];
    K[base]      = (_Float16)(k1 * c - k2 * sn);
    K[base + 64] = (_Float16)(k2 * c + k1 * sn);
  } else {
    const int b2 = bid - 8192;
    const int r0 = (b2 >> 5) * 64, c0 = (b2 & 31) * 64;
    const int tr = threadIdx.x >> 3, tc = (threadIdx.x & 7) * 8;
    #pragma unroll
    for (int p = 0; p < 2; ++p) {
      half8 v = *(const half8*)(V + (size_t)(r0 + p * 32 + tr) * 2048 + c0 + tc);
      *(half8*)&t[p * 32 + tr][tc] = v;
    }
    __syncthreads();
    #pragma unroll
    for (int p = 0; p < 2; ++p) {
      half8 v;
      #pragma unroll
      for (int j = 0; j < 8; ++j) v[j] = t[tc + j][p * 32 + tr];
      *(half8*)(Vt + (size_t)(c0 + p * 32 + tr) * 2048 + r0 + tc) = v;
    }
  }
}

// ---------------------------------------------------------------- fused QKV GEMM, 256x192 tiles
// C[2048, 6144] = X[2048,2048] * W[6144,2048]^T. Grid 32x8 = 256 blocks = 1/CU.
// 8 waves (2M x 4N); BK=64; A triple-, B double-buffered; counted vmcnt(4) steady state
// (round-8 ledger, verified). NEW vs round-8: 2 phases per K-tile (kh halves) instead
// of 4 -- af[8] and bf[3] each read ONCE (was: bf read twice), 24 MFMA per phase,
// barriers halved. Per-wave LDS reads per K-tile 28KB -> 22KB (the measured binding
// resource: 8 waves x 7KB/phase = 660cy LDS vs 387cy MFMA -> MfmaUtil 33.5%).
__global__ __launch_bounds__(512, 1) void gemm_qkv(const _Float16* __restrict__ A,
                                                   const _Float16* __restrict__ W,
                                                   _Float16* __restrict__ Cq) {
  extern __shared__ _Float16 lds[];
  _Float16* As = lds;                // [3][256*64]
  _Float16* Bs = lds + 3 * 16384;    // [2][192*64]

  const int tid = threadIdx.x, lane = tid & 63, wv = tid >> 6;
  const int fr = lane & 15, fg = lane >> 4;
  const int wm = wv >> 2, wn = wv & 3;
  const int bm = blockIdx.y * 256, bn = blockIdx.x * 192;
  const _Float16* Ab = A + (size_t)bm * 2048;
  const _Float16* Bb = W + (size_t)bn * 2048;

  const int srow = lane >> 3;                  // 0..7
  const int sgr = (lane & 7) ^ srow;           // pre-swizzled source granule

  auto stageA = [&](int t) {                   // 4 ops/wave, 256 rows
    _Float16* dst = As + (t % 3) * 16384;
    const size_t coff = (size_t)t * 64 + sgr * 8;
    #pragma unroll
    for (int i = 0; i < 4; ++i) {
      const int rb = wv * 32 + i * 8;
      GLDS(Ab + (size_t)(rb + srow) * 2048 + coff, dst + rb * 64);
    }
  };
  auto stageB = [&](int t) {                   // 3 ops/wave, 192 rows
    _Float16* dst = Bs + (t & 1) * 12288;
    const size_t coff = (size_t)t * 64 + sgr * 8;
    #pragma unroll
    for (int i = 0; i < 3; ++i) {
      const int rb = wv * 24 + i * 8;
      GLDS(Bb + (size_t)(rb + srow) * 2048 + coff, dst + rb * 64);
    }
  };

  const int arow = wm * 128 + fr;
  const int brow = wn * 48 + fr;
  const int sw = fr & 7;

  floatx4 acc[8][3] = {};

  // prologue: A(0), B(0), A(1); certify oldest 7 (A0+B0), keep A1 (4 ops) in flight
  stageA(0); stageB(0); stageA(1);
  asm volatile("s_waitcnt vmcnt(4)" ::: "memory");
  __builtin_amdgcn_s_barrier();

  for (int t = 0; t < 32; ++t) {
    const _Float16* Ac = As + (t % 3) * 16384;
    const _Float16* Bc = Bs + (t & 1) * 12288;
    #pragma unroll
    for (int kh = 0; kh < 2; ++kh) {
      const int sl = ((kh * 4 + fg) ^ sw) * 8;
      half8 af[8], bf[3];
      #pragma unroll
      for (int q = 0; q < 2; ++q)
        #pragma unroll
        for (int m = 0; m < 4; ++m)
          af[q * 4 + m] = *(const half8*)(Ac + (arow + q * 64 + m * 16) * 64 + sl);
      #pragma unroll
      for (int n = 0; n < 3; ++n)
        bf[n] = *(const half8*)(Bc + (brow + n * 16) * 64 + sl);
      if (kh == 0 && t + 1 < 32) stageB(t + 1);
      if (kh == 1 && t + 2 < 32) stageA(t + 2);
      __builtin_amdgcn_s_barrier();
      asm volatile("s_waitcnt lgkmcnt(0)" ::: "memory");
      __builtin_amdgcn_sched_barrier(0);
      __builtin_amdgcn_s_setprio(1);
      #pragma unroll
      for (int q = 0; q < 2; ++q)
        #pragma unroll
        for (int m = 0; m < 4; ++m)
          #pragma unroll
          for (int n = 0; n < 3; ++n)
            acc[q * 4 + m][n] =
                __builtin_amdgcn_mfma_f32_16x16x32_f16(af[q * 4 + m], bf[n],
                                                       acc[q * 4 + m][n], 0, 0, 0);
      __builtin_amdgcn_s_setprio(0);
      if (kh == 1) {
        if (t < 30)       asm volatile("s_waitcnt vmcnt(4)" ::: "memory");
        else if (t == 30) asm volatile("s_waitcnt vmcnt(0)" ::: "memory");
      }
      __builtin_amdgcn_s_barrier();
    }
  }

  #pragma unroll
  for (int m = 0; m < 8; ++m)
    #pragma unroll
    for (int n = 0; n < 3; ++n)
      #pragma unroll
      for (int i = 0; i < 4; ++i) {
        const int row = bm + wm * 128 + m * 16 + fg * 4 + i;
        const int col = bn + wn * 48 + n * 16 + fr;       // 0..6143
        Cq[(size_t)(col >> 11) * 4194304 + (size_t)row * 2048 + (col & 2047)] =
            (_Float16)acc[m][n][i];
      }
}

// ---------------------------------------------------------------- GEMM NT (2-phase, for O-proj)
template <int OUTF, int BN>
__global__ __launch_bounds__(256) void gemm_nt(const _Float16* __restrict__ A,
                                               const _Float16* __restrict__ B,
                                               _Float16* __restrict__ Ch,
                                               float* __restrict__ Cf,
                                               long long bStride, long long cStride) {
  __shared__ _Float16 As[2][128 * 32];
  __shared__ _Float16 Bs[2][BN * 32];
  const int NF = BN / 32;
  const int tid = threadIdx.x, lane = tid & 63, wv = tid >> 6;
  const int fr = lane & 15, fg = lane >> 4;
  const int bm = blockIdx.y * 128, bn = blockIdx.x * BN;
  const _Float16* Ab = A + (size_t)bm * 2048;
  const _Float16* Bb = B + (size_t)blockIdx.z * bStride + (size_t)bn * 2048;
  const int srow = lane >> 2;
  const int gsw = (lane & 3) ^ ((lane >> 3) & 3);
  const int asw = (fr >> 1) & 3;

  floatx4 acc[4][NF] = {};

  auto stage = [&](int buf, int kt) {
    #pragma unroll
    for (int r = 0; r < 2; ++r) {
      int row = r * 64 + wv * 16 + srow;
      GLDS(Ab + (size_t)row * 2048 + kt * 32 + gsw * 8, &As[buf][(r * 64 + wv * 16) * 32]);
    }
    #pragma unroll
    for (int r = 0; r < BN / 64; ++r) {
      int row = r * 64 + wv * 16 + srow;
      GLDS(Bb + (size_t)row * 2048 + kt * 32 + gsw * 8, &Bs[buf][(r * 64 + wv * 16) * 32]);
    }
  };
  const int wm = (wv >> 1) * 64, wn = (wv & 1) * (BN / 2);

  stage(0, 0);
  __syncthreads();

  #pragma unroll 2
  for (int kt = 0; kt < 64; ++kt) {
    const int cur = kt & 1;
    if (kt < 63) stage(cur ^ 1, kt + 1);
    half8 af[4], bf[NF];
    #pragma unroll
    for (int m = 0; m < 4; ++m)
      af[m] = *(const half8*)&As[cur][(wm + m * 16 + fr) * 32 + ((fg ^ asw) * 8)];
    #pragma unroll
    for (int n = 0; n < NF; ++n)
      bf[n] = *(const half8*)&Bs[cur][(wn + n * 16 + fr) * 32 + ((fg ^ asw) * 8)];
    #pragma unroll
    for (int m = 0; m < 4; ++m)
      #pragma unroll
      for (int n = 0; n < NF; ++n)
        acc[m][n] = __builtin_amdgcn_mfma_f32_16x16x32_f16(af[m], bf[n], acc[m][n], 0, 0, 0);
    __syncthreads();
  }

  #pragma unroll
  for (int m = 0; m < 4; ++m)
    #pragma unroll
    for (int n = 0; n < NF; ++n)
      #pragma unroll
      for (int i = 0; i < 4; ++i) {
        const int row = bm + wm + m * 16 + fg * 4 + i;
        const int col = bn + wn + n * 16 + fr;
        if (OUTF)
          Cf[(size_t)row * 2048 + col] = acc[m][n][i];
        else
          Ch[(size_t)blockIdx.z * cStride + (size_t)row * 2048 + col] = (_Float16)acc[m][n][i];
      }
}

// ---------------------------------------------------------------- causal flash attention (32x32 MFMA)
// 768 blocks; unit (head, L) -> (g, kv-chunk); writes UNNORMALIZED partial O + sum-exp.
__global__ __launch_bounds__(256, 2) void attn_k(const _Float16* __restrict__ Qp,
                                                 const _Float16* __restrict__ Kp,
                                                 const _Float16* __restrict__ Vt,
                                                 _Float16* __restrict__ Po,
                                                 float* __restrict__ Pr) {
  extern __shared__ _Float16 smem[];
  _Float16* Ks = smem;                    // [2][64*128]
  _Float16* Vs = smem + 2 * 64 * 128;     // [2][128*64]
  _Float16* Pb = smem + 4 * 64 * 128;     // [4][32*40]

  const int tid = threadIdx.x, lane = tid & 63, wv = tid >> 6;
  const int l31 = lane & 31, hi = lane >> 5;
  const int wq = wv >> 1, wk = wv & 1;

  const int bid = (int)blockIdx.x;
  const int head = ((bid & 7) << 1) | ((bid >> 3) & 1);  // 2 heads per XCD
  const int L = bid >> 4;                                // 0..47
  int g, it0, itEnd;
  if (L < 16) { g = 16 + L; it0 = 0; itEnd = 16; }
  else {
    const int j = (L - 16) >> 1;
    if ((L & 1) == 0) { g = 15 - j; it0 = 0; itEnd = g + 1; }
    else             { g = 31 - j; it0 = 16; itEnd = g + 1; }
  }
  const size_t hoff = (size_t)head * 128;
  const int qw = g * 64 + wq * 32;
  _Float16* Pw = Pb + wv * (32 * 40);

  half8 qf[8];
  const _Float16 scl = (_Float16)0.08838834764831845f;
  #pragma unroll
  for (int ks = 0; ks < 8; ++ks) {
    half8 t = *(const half8*)(Qp + (size_t)(qw + l31) * 2048 + hoff + ks * 16 + hi * 8);
    #pragma unroll
    for (int j = 0; j < 8; ++j) t[j] = (_Float16)(t[j] * scl);
    qf[ks] = t;
  }

  auto stage = [&](int buf, int it) {
    const int kv0 = it * 64;
    #pragma unroll
    for (int i = 0; i < 4; ++i) {       // K: 4 rows per 1KB op
      const int rbase = wv * 16 + i * 4;
      const int row = rbase + (lane >> 4);
      const int gr = (lane & 15) ^ (row & 7);
      GLDS(Kp + (size_t)(kv0 + row) * 2048 + hoff + gr * 8,
           Ks + buf * 8192 + rbase * 128);
    }
    #pragma unroll
    for (int i = 0; i < 4; ++i) {       // V^T: 8 rows per 1KB op
      const int rbase = wv * 32 + i * 8;
      const int row = rbase + (lane >> 3);
      const int gr = (lane & 7) ^ (row & 7);
      GLDS(Vt + (size_t)(hoff + row) * 2048 + kv0 + gr * 8,
           Vs + buf * 8192 + rbase * 64);
    }
  };

  floatx16 o[4] = {};
  float rsum = 0.0f;

  stage(0, it0);
  __syncthreads();

  int buf = 0;
  for (int it = it0; it < itEnd; ++it) {
    if (it + 1 < itEnd) stage(buf ^ 1, it + 1);
    const _Float16* Kb = Ks + buf * 8192;
    const _Float16* Vb = Vs + buf * 8192;

    const int krow = wk * 32 + l31;
    const int ksw = l31 & 7;
    floatx16 S = {};
    __builtin_amdgcn_s_setprio(1);
    #pragma unroll
    for (int ks = 0; ks < 8; ++ks) {
      half8 a = *(const half8*)(Kb + krow * 128 + (((ks * 2 + hi) ^ ksw) * 8));
      S = __builtin_amdgcn_mfma_f32_32x32x16_f16(a, qf[ks], S, 0, 0, 0);
    }
    __builtin_amdgcn_s_setprio(0);

    if (it == g) {
      const int kv0 = it * 64;
      const int qa = qw + l31;
      #pragma unroll
      for (int r = 0; r < 16; ++r) {
        const int ka = kv0 + wk * 32 + (r & 3) + 8 * (r >> 2) + 4 * hi;
        if (ka > qa) S[r] = -1e30f;
      }
    }

    #pragma unroll
    for (int r4 = 0; r4 < 4; ++r4) {
      float p0 = __expf(S[4 * r4 + 0] - 8.0f);
      float p1 = __expf(S[4 * r4 + 1] - 8.0f);
      float p2 = __expf(S[4 * r4 + 2] - 8.0f);
      float p3 = __expf(S[4 * r4 + 3] - 8.0f);
      rsum += (p0 + p1) + (p2 + p3);
      half4 pk;
      pk[0] = (_Float16)p0; pk[1] = (_Float16)p1;
      pk[2] = (_Float16)p2; pk[3] = (_Float16)p3;
      *(half4*)(Pw + l31 * 40 + r4 * 8 + hi * 4) = pk;
    }

    half8 pa0 = *(const half8*)(Pw + l31 * 40 + hi * 8);
    half8 pa1 = *(const half8*)(Pw + l31 * 40 + 16 + hi * 8);

    __builtin_amdgcn_s_setprio(1);
    #pragma unroll
    for (int dt = 0; dt < 4; ++dt) {
      const int vrow = dt * 32 + l31;
      const int vsw = vrow & 7;
      half8 b0 = *(const half8*)(Vb + vrow * 64 + (((wk * 4 + hi) ^ vsw) * 8));
      half8 b1 = *(const half8*)(Vb + vrow * 64 + (((wk * 4 + 2 + hi) ^ vsw) * 8));
      o[dt] = __builtin_amdgcn_mfma_f32_32x32x16_f16(pa0, b0, o[dt], 0, 0, 0);
      o[dt] = __builtin_amdgcn_mfma_f32_32x32x16_f16(pa1, b1, o[dt], 0, 0, 0);
    }
    __builtin_amdgcn_s_setprio(0);

    __syncthreads();
    buf ^= 1;
  }

  float* Mo = (float*)smem;
  float* Mr = (float*)(smem + 16384);
  if (wk == 1) {
    #pragma unroll
    for (int dt = 0; dt < 4; ++dt)
      #pragma unroll
      for (int r = 0; r < 16; ++r)
        Mo[((wq * 4 + dt) * 16 + r) * 64 + lane] = o[dt][r];
    Mr[wq * 64 + lane] = rsum;
  }
  __syncthreads();
  if (wk == 0) {
    rsum += Mr[wq * 64 + lane];
    float rs = rsum;
    rs += __shfl_xor(rs, 32);
    if (hi == 0) Pr[(size_t)bid * 64 + wq * 32 + l31] = rs;
    #pragma unroll
    for (int dt = 0; dt < 4; ++dt)
      #pragma unroll
      for (int r = 0; r < 16; ++r) {
        const float w = o[dt][r] + Mo[((wq * 4 + dt) * 16 + r) * 64 + lane];
        const int ql = wq * 32 + (r & 3) + 8 * (r >> 2) + 4 * hi;
        Po[(size_t)bid * 8192 + ql * 128 + dt * 32 + l31] = (_Float16)w;
      }
  }
}

// ---------------------------------------------------------------- merge kv-chunk partials
__global__ __launch_bounds__(256) void attn_merge(const _Float16* __restrict__ Po,
                                                  const float* __restrict__ Pr,
                                                  _Float16* __restrict__ At) {
  const int bidx = (int)blockIdx.x;
  const int h = bidx & 15, g = bidx >> 4;
  const int hb = ((h & 1) << 3) | (h >> 1);
  const int L0 = (g >= 16) ? (g - 16) : (16 + 2 * (15 - g));
  const int U0 = L0 * 16 + hb;
  const bool two = (g >= 16);
  const int U1 = two ? ((17 + 2 * (31 - g)) * 16 + hb) : 0;
  const int t = threadIdx.x;
  const int q = t >> 2, cs = t & 3;
  const float r0 = Pr[(size_t)U0 * 64 + q];
  const float r1 = two ? Pr[(size_t)U1 * 64 + q] : 0.0f;
  const float inv = 1.0f / (r0 + r1);
  const size_t orow = (size_t)(g * 64 + q) * 2048 + h * 128;
  #pragma unroll
  for (int s = 0; s < 4; ++s) {
    const int d0 = (cs + s * 4) * 8;
    half8 a = *(const half8*)(Po + (size_t)U0 * 8192 + q * 128 + d0);
    half8 o;
    if (two) {
      half8 b = *(const half8*)(Po + (size_t)U1 * 8192 + q * 128 + d0);
      #pragma unroll
      for (int j = 0; j < 8; ++j) o[j] = (_Float16)(((float)a[j] + (float)b[j]) * inv);
    } else {
      #pragma unroll
      for (int j = 0; j < 8; ++j) o[j] = (_Float16)((float)a[j] * inv);
    }
    *(half8*)(At + orow + d0) = o;
  }
}

// ---------------------------------------------------------------- launch
extern "C" void kernel_launch(void* const* d_in, const int* in_sizes, int n_in,
                              void* d_out, int out_size, void* d_ws, size_t ws_size,
                              hipStream_t stream) {
  (void)in_sizes; (void)n_in; (void)out_size; (void)ws_size;
  const float* X  = (const float*)d_in[0];
  const float* Wq = (const float*)d_in[1];
  const float* Wk = (const float*)d_in[2];
  const float* Wv = (const float*)d_in[3];
  const float* Wo = (const float*)d_in[4];
  float* out = (float*)d_out;

  const size_t SZ = 2048ull * 2048ull;
  _Float16* ws  = (_Float16*)d_ws;
  _Float16* Xh  = ws + 0 * SZ;
  _Float16* Wqh = ws + 1 * SZ;   // Wq|Wk|Wv contiguous = one 6144x2048 matrix
  _Float16* Wkh = ws + 2 * SZ;
  _Float16* Wvh = ws + 3 * SZ;
  _Float16* Woh = ws + 4 * SZ;
  _Float16* Qp  = ws + 5 * SZ;   // Q|K|V contiguous = C of the fused GEMM
  _Float16* Kp  = ws + 6 * SZ;
  _Float16* Vp  = ws + 7 * SZ;
  _Float16* Vtg = Wqh;            // dead after QKV GEMM -> V^T
  _Float16* At  = Xh;             // dead after QKV GEMM -> attention output
  _Float16* Po  = Wkh;            // dead after QKV GEMM -> attn partials (spans Wkh+Wvh)
  float*    Pr  = (float*)Vp;     // dead after transpose -> chunk sum-exp

  const int n8 = (int)(SZ / 8);
  dim3 blk(256);

  cvt_f2h5<<<dim3(n8 / 256, 5), blk, 0, stream>>>(X, Wq, Wk, Wv, Wo,
                                                  Xh, Wqh, Wkh, Wvh, Woh, n8);

  // fused QKV projection: 256 blocks (1/CU), counted-vmcnt, single-read 2-phase K-tile
  gemm_qkv<<<dim3(32, 8), dim3(512), 147456, stream>>>(Xh, Wqh, Qp);

  // fused RoPE (Q,K) + V transpose
  rope_tr<<<8192 + 1024, blk, 0, stream>>>(Qp, Kp, Vp, Vtg);

  const size_t attn_lds = (4 * 64 * 128 + 4 * 32 * 40) * sizeof(_Float16);  // 75776 B
  attn_k<<<768, blk, attn_lds, stream>>>(Qp, Kp, Vtg, Po, Pr);
  attn_merge<<<512, blk, 0, stream>>>(Po, Pr, At);

  gemm_nt<1, 128><<<dim3(16, 16, 1), blk, 0, stream>>>(At, Woh, nullptr, out, 0, 0);
}

// Round 14
// 149.477 us; speedup vs baseline: 1.2824x; 1.0983x over previous
//
#include <hip/hip_runtime.h>

typedef _Float16 half8 __attribute__((ext_vector_type(8)));
typedef _Float16 half4 __attribute__((ext_vector_type(4)));
typedef float floatx4 __attribute__((ext_vector_type(4)));
typedef float floatx16 __attribute__((ext_vector_type(16)));

#define GLDS(gp, lp) __builtin_amdgcn_global_load_lds( \
    (const __attribute__((address_space(1))) void*)(gp), \
    (__attribute__((address_space(3))) void*)(lp), 16, 0, 0)

// ---------------------------------------------------------------- f32 -> f16 (5 tensors, one launch)
__global__ void cvt_f2h5(const float* __restrict__ s0, const float* __restrict__ s1,
                         const float* __restrict__ s2, const float* __restrict__ s3,
                         const float* __restrict__ s4,
                         _Float16* __restrict__ d0, _Float16* __restrict__ d1,
                         _Float16* __restrict__ d2, _Float16* __restrict__ d3,
                         _Float16* __restrict__ d4, int n8) {
  int i = blockIdx.x * 256 + threadIdx.x;
  if (i >= n8) return;
  const float* s; _Float16* d;
  switch (blockIdx.y) {
    case 0: s = s0; d = d0; break;
    case 1: s = s1; d = d1; break;
    case 2: s = s2; d = d2; break;
    case 3: s = s3; d = d3; break;
    default: s = s4; d = d4; break;
  }
  const float4* s4p = (const float4*)s;
  float4 a = s4p[2 * i], b = s4p[2 * i + 1];
  half8 h;
  h[0] = (_Float16)a.x; h[1] = (_Float16)a.y; h[2] = (_Float16)a.z; h[3] = (_Float16)a.w;
  h[4] = (_Float16)b.x; h[5] = (_Float16)b.y; h[6] = (_Float16)b.z; h[7] = (_Float16)b.w;
  *(half8*)(d + 8 * (size_t)i) = h;
}

// ---------------------------------------------------------------- fused RoPE + V-transpose (one launch)
__global__ __launch_bounds__(256) void rope_tr(_Float16* __restrict__ Q,
                                               _Float16* __restrict__ K,
                                               const _Float16* __restrict__ V,
                                               _Float16* __restrict__ Vt) {
  __shared__ _Float16 t[64][72];
  const int bid = (int)blockIdx.x;
  if (bid < 8192) {
    const int idx = bid * 256 + threadIdx.x;
    const int s = idx >> 10;
    const int hd = idx & 1023;
    const int head = hd >> 6, d = hd & 63;
    const float freq = exp2f((float)d * -0.2076205059304601f);  // 10000^(-d/64)
    const float ang = (float)s * freq;
    float sn, c;
    __sincosf(ang, &sn, &c);
    const size_t base = (size_t)s * 2048 + head * 128 + d;
    float q1 = (float)Q[base], q2 = (float)Q[base + 64];
    Q[base]      = (_Float16)(q1 * c - q2 * sn);
    Q[base + 64] = (_Float16)(q2 * c + q1 * sn);
    float k1 = (float)K[base], k2 = (float)K[base + 64];
    K[base]      = (_Float16)(k1 * c - k2 * sn);
    K[base + 64] = (_Float16)(k2 * c + k1 * sn);
  } else {
    const int b2 = bid - 8192;
    const int r0 = (b2 >> 5) * 64, c0 = (b2 & 31) * 64;
    const int tr = threadIdx.x >> 3, tc = (threadIdx.x & 7) * 8;
    #pragma unroll
    for (int p = 0; p < 2; ++p) {
      half8 v = *(const half8*)(V + (size_t)(r0 + p * 32 + tr) * 2048 + c0 + tc);
      *(half8*)&t[p * 32 + tr][tc] = v;
    }
    __syncthreads();
    #pragma unroll
    for (int p = 0; p < 2; ++p) {
      half8 v;
      #pragma unroll
      for (int j = 0; j < 8; ++j) v[j] = t[tc + j][p * 32 + tr];
      *(half8*)(Vt + (size_t)(c0 + p * 32 + tr) * 2048 + r0 + tc) = v;
    }
  }
}

// ---------------------------------------------------------------- fused QKV GEMM, 256x192 tiles
// C[2048, 6144] = X[2048,2048] * W[6144,2048]^T. Grid 32x8 = 256 blocks = 1/CU.
// 8 waves (2M x 4N); BK=64; A triple-, B double-buffered; counted vmcnt(4) ledger
// (round-8/13, verified). NEW: ONE barrier per K-tile; all 22 fragment reads issued
// up front, NO manual lgkmcnt -- compiler inserts counted lgkm waits per use, so
// kh1's LDS service overlaps kh0's MFMA, and waves drift within the tile (one
// wave's reads overlap another's MFMA on the same SIMD).
__global__ __launch_bounds__(512, 1) void gemm_qkv(const _Float16* __restrict__ A,
                                                   const _Float16* __restrict__ W,
                                                   _Float16* __restrict__ Cq) {
  extern __shared__ _Float16 lds[];
  _Float16* As = lds;                // [3][256*64]
  _Float16* Bs = lds + 3 * 16384;    // [2][192*64]

  const int tid = threadIdx.x, lane = tid & 63, wv = tid >> 6;
  const int fr = lane & 15, fg = lane >> 4;
  const int wm = wv >> 2, wn = wv & 3;
  const int bm = blockIdx.y * 256, bn = blockIdx.x * 192;
  const _Float16* Ab = A + (size_t)bm * 2048;
  const _Float16* Bb = W + (size_t)bn * 2048;

  const int srow = lane >> 3;                  // 0..7
  const int sgr = (lane & 7) ^ srow;           // pre-swizzled source granule

  auto stageA = [&](int t) {                   // 4 ops/wave, 256 rows
    _Float16* dst = As + (t % 3) * 16384;
    const size_t coff = (size_t)t * 64 + sgr * 8;
    #pragma unroll
    for (int i = 0; i < 4; ++i) {
      const int rb = wv * 32 + i * 8;
      GLDS(Ab + (size_t)(rb + srow) * 2048 + coff, dst + rb * 64);
    }
  };
  auto stageB = [&](int t) {                   // 3 ops/wave, 192 rows
    _Float16* dst = Bs + (t & 1) * 12288;
    const size_t coff = (size_t)t * 64 + sgr * 8;
    #pragma unroll
    for (int i = 0; i < 3; ++i) {
      const int rb = wv * 24 + i * 8;
      GLDS(Bb + (size_t)(rb + srow) * 2048 + coff, dst + rb * 64);
    }
  };

  const int arow = wm * 128 + fr;
  const int brow = wn * 48 + fr;
  const int sw = fr & 7;

  floatx4 acc[8][3] = {};

  // prologue: A(0), B(0), A(1); certify oldest 7 (A0+B0), keep A1 (4 ops) in flight
  stageA(0); stageB(0); stageA(1);
  asm volatile("s_waitcnt vmcnt(4)" ::: "memory");
  __builtin_amdgcn_s_barrier();

  for (int t = 0; t < 32; ++t) {
    const _Float16* Ac = As + (t % 3) * 16384;
    const _Float16* Bc = Bs + (t & 1) * 12288;
    half8 af[2][8], bf[2][3];
    #pragma unroll
    for (int kh = 0; kh < 2; ++kh) {
      const int sl = ((kh * 4 + fg) ^ sw) * 8;
      #pragma unroll
      for (int q = 0; q < 2; ++q)
        #pragma unroll
        for (int m = 0; m < 4; ++m)
          af[kh][q * 4 + m] = *(const half8*)(Ac + (arow + q * 64 + m * 16) * 64 + sl);
      #pragma unroll
      for (int n = 0; n < 3; ++n)
        bf[kh][n] = *(const half8*)(Bc + (brow + n * 16) * 64 + sl);
    }
    if (t + 1 < 32) stageB(t + 1);
    if (t + 2 < 32) stageA(t + 2);
    __builtin_amdgcn_s_setprio(1);
    #pragma unroll
    for (int kh = 0; kh < 2; ++kh)
      #pragma unroll
      for (int q = 0; q < 2; ++q)
        #pragma unroll
        for (int m = 0; m < 4; ++m)
          #pragma unroll
          for (int n = 0; n < 3; ++n)
            acc[q * 4 + m][n] =
                __builtin_amdgcn_mfma_f32_16x16x32_f16(af[kh][q * 4 + m], bf[kh][n],
                                                       acc[q * 4 + m][n], 0, 0, 0);
    __builtin_amdgcn_s_setprio(0);
    if (t < 30)       asm volatile("s_waitcnt vmcnt(4)" ::: "memory");
    else if (t == 30) asm volatile("s_waitcnt vmcnt(0)" ::: "memory");
    __builtin_amdgcn_s_barrier();
  }

  #pragma unroll
  for (int m = 0; m < 8; ++m)
    #pragma unroll
    for (int n = 0; n < 3; ++n)
      #pragma unroll
      for (int i = 0; i < 4; ++i) {
        const int row = bm + wm * 128 + m * 16 + fg * 4 + i;
        const int col = bn + wn * 48 + n * 16 + fr;       // 0..6143
        Cq[(size_t)(col >> 11) * 4194304 + (size_t)row * 2048 + (col & 2047)] =
            (_Float16)acc[m][n][i];
      }
}

// ---------------------------------------------------------------- O-projection GEMM, single-barrier
// out[2048,2048] f32 = At[2048,2048] * Wo[2048,2048]^T. 128x128 tiles, 256 blocks,
// 4 waves (2x2), BK=64, A/B double-buffered (64KB -> 2 blocks/CU for cross-block
// overlap). Same skeleton as gemm_qkv: all 16 reads up front, stage(t+1) mid-tile,
// compiler-counted lgkm, vmcnt(0) after a full MFMA cluster of slack, 1 barrier.
__global__ __launch_bounds__(256, 2) void gemm_o(const _Float16* __restrict__ A,
                                                 const _Float16* __restrict__ B,
                                                 float* __restrict__ out) {
  extern __shared__ _Float16 lds[];
  _Float16* As = lds;               // [2][128*64]
  _Float16* Bs = lds + 2 * 8192;    // [2][128*64]

  const int tid = threadIdx.x, lane = tid & 63, wv = tid >> 6;  // 4 waves
  const int fr = lane & 15, fg = lane >> 4;
  const int wm = (wv >> 1) * 64, wn = (wv & 1) * 64;
  const int bm = blockIdx.y * 128, bn = blockIdx.x * 128;
  const _Float16* Ab = A + (size_t)bm * 2048;
  const _Float16* Bb = B + (size_t)bn * 2048;

  const int srow = lane >> 3;
  const int sgr = (lane & 7) ^ srow;
  const int sw = fr & 7;

  auto stageA = [&](int t) {                   // 4 ops/wave, 128 rows
    _Float16* dst = As + (t & 1) * 8192;
    const size_t coff = (size_t)t * 64 + sgr * 8;
    #pragma unroll
    for (int i = 0; i < 4; ++i) {
      const int rb = wv * 32 + i * 8;
      GLDS(Ab + (size_t)(rb + srow) * 2048 + coff, dst + rb * 64);
    }
  };
  auto stageB = [&](int t) {
    _Float16* dst = Bs + (t & 1) * 8192;
    const size_t coff = (size_t)t * 64 + sgr * 8;
    #pragma unroll
    for (int i = 0; i < 4; ++i) {
      const int rb = wv * 32 + i * 8;
      GLDS(Bb + (size_t)(rb + srow) * 2048 + coff, dst + rb * 64);
    }
  };

  floatx4 acc[4][4] = {};

  stageA(0); stageB(0);
  asm volatile("s_waitcnt vmcnt(0)" ::: "memory");
  __builtin_amdgcn_s_barrier();

  for (int t = 0; t < 32; ++t) {
    const _Float16* Ac = As + (t & 1) * 8192;
    const _Float16* Bc = Bs + (t & 1) * 8192;
    half8 af[2][4], bf[2][4];
    #pragma unroll
    for (int kh = 0; kh < 2; ++kh) {
      const int sl = ((kh * 4 + fg) ^ sw) * 8;
      #pragma unroll
      for (int m = 0; m < 4; ++m)
        af[kh][m] = *(const half8*)(Ac + (wm + m * 16 + fr) * 64 + sl);
      #pragma unroll
      for (int n = 0; n < 4; ++n)
        bf[kh][n] = *(const half8*)(Bc + (wn + n * 16 + fr) * 64 + sl);
    }
    if (t + 1 < 32) { stageA(t + 1); stageB(t + 1); }
    __builtin_amdgcn_s_setprio(1);
    #pragma unroll
    for (int kh = 0; kh < 2; ++kh)
      #pragma unroll
      for (int m = 0; m < 4; ++m)
        #pragma unroll
        for (int n = 0; n < 4; ++n)
          acc[m][n] = __builtin_amdgcn_mfma_f32_16x16x32_f16(af[kh][m], bf[kh][n],
                                                             acc[m][n], 0, 0, 0);
    __builtin_amdgcn_s_setprio(0);
    asm volatile("s_waitcnt vmcnt(0)" ::: "memory");
    __builtin_amdgcn_s_barrier();
  }

  #pragma unroll
  for (int m = 0; m < 4; ++m)
    #pragma unroll
    for (int n = 0; n < 4; ++n)
      #pragma unroll
      for (int i = 0; i < 4; ++i) {
        const int row = bm + wm + m * 16 + fg * 4 + i;
        const int col = bn + wn + n * 16 + fr;
        out[(size_t)row * 2048 + col] = acc[m][n][i];
      }
}

// ---------------------------------------------------------------- causal flash attention (32x32 MFMA)
// 768 blocks; unit (head, L) -> (g, kv-chunk); writes UNNORMALIZED partial O + sum-exp.
__global__ __launch_bounds__(256, 2) void attn_k(const _Float16* __restrict__ Qp,
                                                 const _Float16* __restrict__ Kp,
                                                 const _Float16* __restrict__ Vt,
                                                 _Float16* __restrict__ Po,
                                                 float* __restrict__ Pr) {
  extern __shared__ _Float16 smem[];
  _Float16* Ks = smem;                    // [2][64*128]
  _Float16* Vs = smem + 2 * 64 * 128;     // [2][128*64]
  _Float16* Pb = smem + 4 * 64 * 128;     // [4][32*40]

  const int tid = threadIdx.x, lane = tid & 63, wv = tid >> 6;
  const int l31 = lane & 31, hi = lane >> 5;
  const int wq = wv >> 1, wk = wv & 1;

  const int bid = (int)blockIdx.x;
  const int head = ((bid & 7) << 1) | ((bid >> 3) & 1);  // 2 heads per XCD
  const int L = bid >> 4;                                // 0..47
  int g, it0, itEnd;
  if (L < 16) { g = 16 + L; it0 = 0; itEnd = 16; }
  else {
    const int j = (L - 16) >> 1;
    if ((L & 1) == 0) { g = 15 - j; it0 = 0; itEnd = g + 1; }
    else             { g = 31 - j; it0 = 16; itEnd = g + 1; }
  }
  const size_t hoff = (size_t)head * 128;
  const int qw = g * 64 + wq * 32;
  _Float16* Pw = Pb + wv * (32 * 40);

  half8 qf[8];
  const _Float16 scl = (_Float16)0.08838834764831845f;
  #pragma unroll
  for (int ks = 0; ks < 8; ++ks) {
    half8 t = *(const half8*)(Qp + (size_t)(qw + l31) * 2048 + hoff + ks * 16 + hi * 8);
    #pragma unroll
    for (int j = 0; j < 8; ++j) t[j] = (_Float16)(t[j] * scl);
    qf[ks] = t;
  }

  auto stage = [&](int buf, int it) {
    const int kv0 = it * 64;
    #pragma unroll
    for (int i = 0; i < 4; ++i) {       // K: 4 rows per 1KB op
      const int rbase = wv * 16 + i * 4;
      const int row = rbase + (lane >> 4);
      const int gr = (lane & 15) ^ (row & 7);
      GLDS(Kp + (size_t)(kv0 + row) * 2048 + hoff + gr * 8,
           Ks + buf * 8192 + rbase * 128);
    }
    #pragma unroll
    for (int i = 0; i < 4; ++i) {       // V^T: 8 rows per 1KB op
      const int rbase = wv * 32 + i * 8;
      const int row = rbase + (lane >> 3);
      const int gr = (lane & 7) ^ (row & 7);
      GLDS(Vt + (size_t)(hoff + row) * 2048 + kv0 + gr * 8,
           Vs + buf * 8192 + rbase * 64);
    }
  };

  floatx16 o[4] = {};
  float rsum = 0.0f;

  stage(0, it0);
  __syncthreads();

  int buf = 0;
  for (int it = it0; it < itEnd; ++it) {
    if (it + 1 < itEnd) stage(buf ^ 1, it + 1);
    const _Float16* Kb = Ks + buf * 8192;
    const _Float16* Vb = Vs + buf * 8192;

    const int krow = wk * 32 + l31;
    const int ksw = l31 & 7;
    floatx16 S = {};
    __builtin_amdgcn_s_setprio(1);
    #pragma unroll
    for (int ks = 0; ks < 8; ++ks) {
      half8 a = *(const half8*)(Kb + krow * 128 + (((ks * 2 + hi) ^ ksw) * 8));
      S = __builtin_amdgcn_mfma_f32_32x32x16_f16(a, qf[ks], S, 0, 0, 0);
    }
    __builtin_amdgcn_s_setprio(0);

    if (it == g) {
      const int kv0 = it * 64;
      const int qa = qw + l31;
      #pragma unroll
      for (int r = 0; r < 16; ++r) {
        const int ka = kv0 + wk * 32 + (r & 3) + 8 * (r >> 2) + 4 * hi;
        if (ka > qa) S[r] = -1e30f;
      }
    }

    #pragma unroll
    for (int r4 = 0; r4 < 4; ++r4) {
      float p0 = __expf(S[4 * r4 + 0] - 8.0f);
      float p1 = __expf(S[4 * r4 + 1] - 8.0f);
      float p2 = __expf(S[4 * r4 + 2] - 8.0f);
      float p3 = __expf(S[4 * r4 + 3] - 8.0f);
      rsum += (p0 + p1) + (p2 + p3);
      half4 pk;
      pk[0] = (_Float16)p0; pk[1] = (_Float16)p1;
      pk[2] = (_Float16)p2; pk[3] = (_Float16)p3;
      *(half4*)(Pw + l31 * 40 + r4 * 8 + hi * 4) = pk;
    }

    half8 pa0 = *(const half8*)(Pw + l31 * 40 + hi * 8);
    half8 pa1 = *(const half8*)(Pw + l31 * 40 + 16 + hi * 8);

    __builtin_amdgcn_s_setprio(1);
    #pragma unroll
    for (int dt = 0; dt < 4; ++dt) {
      const int vrow = dt * 32 + l31;
      const int vsw = vrow & 7;
      half8 b0 = *(const half8*)(Vb + vrow * 64 + (((wk * 4 + hi) ^ vsw) * 8));
      half8 b1 = *(const half8*)(Vb + vrow * 64 + (((wk * 4 + 2 + hi) ^ vsw) * 8));
      o[dt] = __builtin_amdgcn_mfma_f32_32x32x16_f16(pa0, b0, o[dt], 0, 0, 0);
      o[dt] = __builtin_amdgcn_mfma_f32_32x32x16_f16(pa1, b1, o[dt], 0, 0, 0);
    }
    __builtin_amdgcn_s_setprio(0);

    __syncthreads();
    buf ^= 1;
  }

  float* Mo = (float*)smem;
  float* Mr = (float*)(smem + 16384);
  if (wk == 1) {
    #pragma unroll
    for (int dt = 0; dt < 4; ++dt)
      #pragma unroll
      for (int r = 0; r < 16; ++r)
        Mo[((wq * 4 + dt) * 16 + r) * 64 + lane] = o[dt][r];
    Mr[wq * 64 + lane] = rsum;
  }
  __syncthreads();
  if (wk == 0) {
    rsum += Mr[wq * 64 + lane];
    float rs = rsum;
    rs += __shfl_xor(rs, 32);
    if (hi == 0) Pr[(size_t)bid * 64 + wq * 32 + l31] = rs;
    #pragma unroll
    for (int dt = 0; dt < 4; ++dt)
      #pragma unroll
      for (int r = 0; r < 16; ++r) {
        const float w = o[dt][r] + Mo[((wq * 4 + dt) * 16 + r) * 64 + lane];
        const int ql = wq * 32 + (r & 3) + 8 * (r >> 2) + 4 * hi;
        Po[(size_t)bid * 8192 + ql * 128 + dt * 32 + l31] = (_Float16)w;
      }
  }
}

// ---------------------------------------------------------------- merge kv-chunk partials
__global__ __launch_bounds__(256) void attn_merge(const _Float16* __restrict__ Po,
                                                  const float* __restrict__ Pr,
                                                  _Float16* __restrict__ At) {
  const int bidx = (int)blockIdx.x;
  const int h = bidx & 15, g = bidx >> 4;
  const int hb = ((h & 1) << 3) | (h >> 1);
  const int L0 = (g >= 16) ? (g - 16) : (16 + 2 * (15 - g));
  const int U0 = L0 * 16 + hb;
  const bool two = (g >= 16);
  const int U1 = two ? ((17 + 2 * (31 - g)) * 16 + hb) : 0;
  const int t = threadIdx.x;
  const int q = t >> 2, cs = t & 3;
  const float r0 = Pr[(size_t)U0 * 64 + q];
  const float r1 = two ? Pr[(size_t)U1 * 64 + q] : 0.0f;
  const float inv = 1.0f / (r0 + r1);
  const size_t orow = (size_t)(g * 64 + q) * 2048 + h * 128;
  #pragma unroll
  for (int s = 0; s < 4; ++s) {
    const int d0 = (cs + s * 4) * 8;
    half8 a = *(const half8*)(Po + (size_t)U0 * 8192 + q * 128 + d0);
    half8 o;
    if (two) {
      half8 b = *(const half8*)(Po + (size_t)U1 * 8192 + q * 128 + d0);
      #pragma unroll
      for (int j = 0; j < 8; ++j) o[j] = (_Float16)(((float)a[j] + (float)b[j]) * inv);
    } else {
      #pragma unroll
      for (int j = 0; j < 8; ++j) o[j] = (_Float16)((float)a[j] * inv);
    }
    *(half8*)(At + orow + d0) = o;
  }
}

// ---------------------------------------------------------------- launch
extern "C" void kernel_launch(void* const* d_in, const int* in_sizes, int n_in,
                              void* d_out, int out_size, void* d_ws, size_t ws_size,
                              hipStream_t stream) {
  (void)in_sizes; (void)n_in; (void)out_size; (void)ws_size;
  const float* X  = (const float*)d_in[0];
  const float* Wq = (const float*)d_in[1];
  const float* Wk = (const float*)d_in[2];
  const float* Wv = (const float*)d_in[3];
  const float* Wo = (const float*)d_in[4];
  float* out = (float*)d_out;

  const size_t SZ = 2048ull * 2048ull;
  _Float16* ws  = (_Float16*)d_ws;
  _Float16* Xh  = ws + 0 * SZ;
  _Float16* Wqh = ws + 1 * SZ;   // Wq|Wk|Wv contiguous = one 6144x2048 matrix
  _Float16* Wkh = ws + 2 * SZ;
  _Float16* Wvh = ws + 3 * SZ;
  _Float16* Woh = ws + 4 * SZ;
  _Float16* Qp  = ws + 5 * SZ;   // Q|K|V contiguous = C of the fused GEMM
  _Float16* Kp  = ws + 6 * SZ;
  _Float16* Vp  = ws + 7 * SZ;
  _Float16* Vtg = Wqh;            // dead after QKV GEMM -> V^T
  _Float16* At  = Xh;             // dead after QKV GEMM -> attention output
  _Float16* Po  = Wkh;            // dead after QKV GEMM -> attn partials (spans Wkh+Wvh)
  float*    Pr  = (float*)Vp;     // dead after transpose -> chunk sum-exp

  const int n8 = (int)(SZ / 8);
  dim3 blk(256);

  cvt_f2h5<<<dim3(n8 / 256, 5), blk, 0, stream>>>(X, Wq, Wk, Wv, Wo,
                                                  Xh, Wqh, Wkh, Wvh, Woh, n8);

  // fused QKV projection: 256 blocks (1/CU), single-barrier K-tile, counted vmcnt
  gemm_qkv<<<dim3(32, 8), dim3(512), 147456, stream>>>(Xh, Wqh, Qp);

  // fused RoPE (Q,K) + V transpose
  rope_tr<<<8192 + 1024, blk, 0, stream>>>(Qp, Kp, Vp, Vtg);

  const size_t attn_lds = (4 * 64 * 128 + 4 * 32 * 40) * sizeof(_Float16);  // 75776 B
  attn_k<<<768, blk, attn_lds, stream>>>(Qp, Kp, Vtg, Po, Pr);
  attn_merge<<<512, blk, 0, stream>>>(Po, Pr, At);

  // O-projection: single-barrier skeleton, 2 blocks/CU
  gemm_o<<<dim3(16, 16), blk, 65536, stream>>>(At, Woh, out);
}

// Round 15
// 148.969 us; speedup vs baseline: 1.2868x; 1.0034x over previous
//
#include <hip/hip_runtime.h>

typedef _Float16 half8 __attribute__((ext_vector_type(8)));
typedef _Float16 half4 __attribute__((ext_vector_type(4)));
typedef float floatx4 __attribute__((ext_vector_type(4)));
typedef float floatx16 __attribute__((ext_vector_type(16)));

#define GLDS(gp, lp) __builtin_amdgcn_global_load_lds( \
    (const __attribute__((address_space(1))) void*)(gp), \
    (__attribute__((address_space(3))) void*)(lp), 16, 0, 0)

// ---------------------------------------------------------------- f32 -> f16 (5 tensors, one launch)
__global__ void cvt_f2h5(const float* __restrict__ s0, const float* __restrict__ s1,
                         const float* __restrict__ s2, const float* __restrict__ s3,
                         const float* __restrict__ s4,
                         _Float16* __restrict__ d0, _Float16* __restrict__ d1,
                         _Float16* __restrict__ d2, _Float16* __restrict__ d3,
                         _Float16* __restrict__ d4, int n8) {
  int i = blockIdx.x * 256 + threadIdx.x;
  if (i >= n8) return;
  const float* s; _Float16* d;
  switch (blockIdx.y) {
    case 0: s = s0; d = d0; break;
    case 1: s = s1; d = d1; break;
    case 2: s = s2; d = d2; break;
    case 3: s = s3; d = d3; break;
    default: s = s4; d = d4; break;
  }
  const float4* s4p = (const float4*)s;
  float4 a = s4p[2 * i], b = s4p[2 * i + 1];
  half8 h;
  h[0] = (_Float16)a.x; h[1] = (_Float16)a.y; h[2] = (_Float16)a.z; h[3] = (_Float16)a.w;
  h[4] = (_Float16)b.x; h[5] = (_Float16)b.y; h[6] = (_Float16)b.z; h[7] = (_Float16)b.w;
  *(half8*)(d + 8 * (size_t)i) = h;
}

// ---------------------------------------------------------------- fused RoPE + V-transpose (one launch)
__global__ __launch_bounds__(256) void rope_tr(_Float16* __restrict__ Q,
                                               _Float16* __restrict__ K,
                                               const _Float16* __restrict__ V,
                                               _Float16* __restrict__ Vt) {
  __shared__ _Float16 t[64][72];
  const int bid = (int)blockIdx.x;
  if (bid < 8192) {
    const int idx = bid * 256 + threadIdx.x;
    const int s = idx >> 10;
    const int hd = idx & 1023;
    const int head = hd >> 6, d = hd & 63;
    const float freq = exp2f((float)d * -0.2076205059304601f);  // 10000^(-d/64)
    const float ang = (float)s * freq;
    float sn, c;
    __sincosf(ang, &sn, &c);
    const size_t base = (size_t)s * 2048 + head * 128 + d;
    float q1 = (float)Q[base], q2 = (float)Q[base + 64];
    Q[base]      = (_Float16)(q1 * c - q2 * sn);
    Q[base + 64] = (_Float16)(q2 * c + q1 * sn);
    float k1 = (float)K[base], k2 = (float)K[base + 64];
    K[base]      = (_Float16)(k1 * c - k2 * sn);
    K[base + 64] = (_Float16)(k2 * c + k1 * sn);
  } else {
    const int b2 = bid - 8192;
    const int r0 = (b2 >> 5) * 64, c0 = (b2 & 31) * 64;
    const int tr = threadIdx.x >> 3, tc = (threadIdx.x & 7) * 8;
    #pragma unroll
    for (int p = 0; p < 2; ++p) {
      half8 v = *(const half8*)(V + (size_t)(r0 + p * 32 + tr) * 2048 + c0 + tc);
      *(half8*)&t[p * 32 + tr][tc] = v;
    }
    __syncthreads();
    #pragma unroll
    for (int p = 0; p < 2; ++p) {
      half8 v;
      #pragma unroll
      for (int j = 0; j < 8; ++j) v[j] = t[tc + j][p * 32 + tr];
      *(half8*)(Vt + (size_t)(c0 + p * 32 + tr) * 2048 + r0 + tc) = v;
    }
  }
}

// ---------------------------------------------------------------- fused QKV GEMM, 256x192 tiles
// C[2048, 6144] = X[2048,2048] * W[6144,2048]^T. Grid 32x8 = 256 blocks = 1/CU.
// 8 waves, NOW 4M x 2N (wave 64x96): per-wave LDS reads (64+96)*128B = 20KB/K-tile
// vs 22KB for 2Mx4N -- LDS reads are the measured binding resource (MfmaUtil 43%).
// Single barrier per K-tile, all reads up front, compiler-counted lgkm (round-14,
// verified). A triple-, B double-buffered; counted vmcnt(4) ledger (verified).
__global__ __launch_bounds__(512, 1) void gemm_qkv(const _Float16* __restrict__ A,
                                                   const _Float16* __restrict__ W,
                                                   _Float16* __restrict__ Cq) {
  extern __shared__ _Float16 lds[];
  _Float16* As = lds;                // [3][256*64]
  _Float16* Bs = lds + 3 * 16384;    // [2][192*64]

  const int tid = threadIdx.x, lane = tid & 63, wv = tid >> 6;
  const int fr = lane & 15, fg = lane >> 4;
  const int wm = wv >> 1, wn = wv & 1;         // 4M x 2N
  const int bm = blockIdx.y * 256, bn = blockIdx.x * 192;
  const _Float16* Ab = A + (size_t)bm * 2048;
  const _Float16* Bb = W + (size_t)bn * 2048;

  const int srow = lane >> 3;                  // 0..7
  const int sgr = (lane & 7) ^ srow;           // pre-swizzled source granule

  auto stageA = [&](int t) {                   // 4 ops/wave, 256 rows
    _Float16* dst = As + (t % 3) * 16384;
    const size_t coff = (size_t)t * 64 + sgr * 8;
    #pragma unroll
    for (int i = 0; i < 4; ++i) {
      const int rb = wv * 32 + i * 8;
      GLDS(Ab + (size_t)(rb + srow) * 2048 + coff, dst + rb * 64);
    }
  };
  auto stageB = [&](int t) {                   // 3 ops/wave, 192 rows
    _Float16* dst = Bs + (t & 1) * 12288;
    const size_t coff = (size_t)t * 64 + sgr * 8;
    #pragma unroll
    for (int i = 0; i < 3; ++i) {
      const int rb = wv * 24 + i * 8;
      GLDS(Bb + (size_t)(rb + srow) * 2048 + coff, dst + rb * 64);
    }
  };

  const int arow = wm * 64 + fr;
  const int brow = wn * 96 + fr;
  const int sw = fr & 7;

  floatx4 acc[4][6] = {};

  // prologue: A(0), B(0), A(1); certify oldest 7 (A0+B0), keep A1 (4 ops) in flight
  stageA(0); stageB(0); stageA(1);
  asm volatile("s_waitcnt vmcnt(4)" ::: "memory");
  __builtin_amdgcn_s_barrier();

  for (int t = 0; t < 32; ++t) {
    const _Float16* Ac = As + (t % 3) * 16384;
    const _Float16* Bc = Bs + (t & 1) * 12288;
    half8 af[2][4], bf[2][6];
    #pragma unroll
    for (int kh = 0; kh < 2; ++kh) {
      const int sl = ((kh * 4 + fg) ^ sw) * 8;
      #pragma unroll
      for (int m = 0; m < 4; ++m)
        af[kh][m] = *(const half8*)(Ac + (arow + m * 16) * 64 + sl);
      #pragma unroll
      for (int n = 0; n < 6; ++n)
        bf[kh][n] = *(const half8*)(Bc + (brow + n * 16) * 64 + sl);
    }
    if (t + 1 < 32) stageB(t + 1);
    if (t + 2 < 32) stageA(t + 2);
    __builtin_amdgcn_s_setprio(1);
    #pragma unroll
    for (int kh = 0; kh < 2; ++kh)
      #pragma unroll
      for (int m = 0; m < 4; ++m)
        #pragma unroll
        for (int n = 0; n < 6; ++n)
          acc[m][n] = __builtin_amdgcn_mfma_f32_16x16x32_f16(af[kh][m], bf[kh][n],
                                                             acc[m][n], 0, 0, 0);
    __builtin_amdgcn_s_setprio(0);
    if (t < 30)       asm volatile("s_waitcnt vmcnt(4)" ::: "memory");
    else if (t == 30) asm volatile("s_waitcnt vmcnt(0)" ::: "memory");
    __builtin_amdgcn_s_barrier();
  }

  #pragma unroll
  for (int m = 0; m < 4; ++m)
    #pragma unroll
    for (int n = 0; n < 6; ++n)
      #pragma unroll
      for (int i = 0; i < 4; ++i) {
        const int row = bm + wm * 64 + m * 16 + fg * 4 + i;
        const int col = bn + wn * 96 + n * 16 + fr;       // 0..6143
        Cq[(size_t)(col >> 11) * 4194304 + (size_t)row * 2048 + (col & 2047)] =
            (_Float16)acc[m][n][i];
      }
}

// ---------------------------------------------------------------- O-projection GEMM
// out[2048,2048] f32 = At * Wo^T. 128x128 tiles, 256 blocks, 4 waves (2x2, wave 64x64),
// BK=32, A/B TRIPLE-buffered (48KB -> 3 blocks/CU), counted vmcnt(4) (never drains
// in steady state), single barrier per K-step. Swizzle: BK=32 granule^((row>>1)&3)
// pattern (round-6 verified conflict-free).
__global__ __launch_bounds__(256, 3) void gemm_o(const _Float16* __restrict__ A,
                                                 const _Float16* __restrict__ B,
                                                 float* __restrict__ out) {
  extern __shared__ _Float16 lds[];
  _Float16* As = lds;               // [3][128*32]
  _Float16* Bs = lds + 3 * 4096;    // [3][128*32]

  const int tid = threadIdx.x, lane = tid & 63, wv = tid >> 6;  // 4 waves
  const int fr = lane & 15, fg = lane >> 4;
  const int wm = (wv >> 1) * 64, wn = (wv & 1) * 64;
  const int bm = blockIdx.y * 128, bn = blockIdx.x * 128;
  const _Float16* Ab = A + (size_t)bm * 2048;
  const _Float16* Bb = B + (size_t)bn * 2048;

  const int srow = lane >> 2;                       // 0..15
  const int gsw = (lane & 3) ^ ((lane >> 3) & 3);   // pre-swizzled source granule
  const int asw = (fr >> 1) & 3;                    // read-side swizzle

  auto stageA = [&](int t) {                        // 2 ops/wave, 128 rows
    _Float16* dst = As + (t % 3) * 4096;
    const size_t coff = (size_t)t * 32 + gsw * 8;
    #pragma unroll
    for (int i = 0; i < 2; ++i) {
      const int rb = wv * 32 + i * 16;
      GLDS(Ab + (size_t)(rb + srow) * 2048 + coff, dst + rb * 32);
    }
  };
  auto stageB = [&](int t) {
    _Float16* dst = Bs + (t % 3) * 4096;
    const size_t coff = (size_t)t * 32 + gsw * 8;
    #pragma unroll
    for (int i = 0; i < 2; ++i) {
      const int rb = wv * 32 + i * 16;
      GLDS(Bb + (size_t)(rb + srow) * 2048 + coff, dst + rb * 32);
    }
  };

  floatx4 acc[4][4] = {};

  // prologue: t0 + t1 staged (4 ops each); certify t0, keep t1 in flight
  stageA(0); stageB(0); stageA(1); stageB(1);
  asm volatile("s_waitcnt vmcnt(4)" ::: "memory");
  __builtin_amdgcn_s_barrier();

  for (int t = 0; t < 64; ++t) {
    const _Float16* Ac = As + (t % 3) * 4096;
    const _Float16* Bc = Bs + (t % 3) * 4096;
    half8 af[4], bf[4];
    #pragma unroll
    for (int m = 0; m < 4; ++m)
      af[m] = *(const half8*)(Ac + (wm + m * 16 + fr) * 32 + ((fg ^ asw) * 8));
    #pragma unroll
    for (int n = 0; n < 4; ++n)
      bf[n] = *(const half8*)(Bc + (wn + n * 16 + fr) * 32 + ((fg ^ asw) * 8));
    if (t + 2 < 64) { stageA(t + 2); stageB(t + 2); }
    __builtin_amdgcn_s_setprio(1);
    #pragma unroll
    for (int m = 0; m < 4; ++m)
      #pragma unroll
      for (int n = 0; n < 4; ++n)
        acc[m][n] = __builtin_amdgcn_mfma_f32_16x16x32_f16(af[m], bf[n], acc[m][n], 0, 0, 0);
    __builtin_amdgcn_s_setprio(0);
    if (t < 62) asm volatile("s_waitcnt vmcnt(4)" ::: "memory");
    else        asm volatile("s_waitcnt vmcnt(0)" ::: "memory");
    __builtin_amdgcn_s_barrier();
  }

  #pragma unroll
  for (int m = 0; m < 4; ++m)
    #pragma unroll
    for (int n = 0; n < 4; ++n)
      #pragma unroll
      for (int i = 0; i < 4; ++i) {
        const int row = bm + wm + m * 16 + fg * 4 + i;
        const int col = bn + wn + n * 16 + fr;
        out[(size_t)row * 2048 + col] = acc[m][n][i];
      }
}

// ---------------------------------------------------------------- causal flash attention (32x32 MFMA)
// 768 blocks; unit (head, L) -> (g, kv-chunk); writes UNNORMALIZED partial O + sum-exp.
// Loop-end sync = vmcnt(0) + s_barrier (no forced lgkm drain; per-wave ds_reads are
// consumed before barrier arrival, glds publish certified by per-wave vmcnt).
__global__ __launch_bounds__(256, 2) void attn_k(const _Float16* __restrict__ Qp,
                                                 const _Float16* __restrict__ Kp,
                                                 const _Float16* __restrict__ Vt,
                                                 _Float16* __restrict__ Po,
                                                 float* __restrict__ Pr) {
  extern __shared__ _Float16 smem[];
  _Float16* Ks = smem;                    // [2][64*128]
  _Float16* Vs = smem + 2 * 64 * 128;     // [2][128*64]
  _Float16* Pb = smem + 4 * 64 * 128;     // [4][32*40]

  const int tid = threadIdx.x, lane = tid & 63, wv = tid >> 6;
  const int l31 = lane & 31, hi = lane >> 5;
  const int wq = wv >> 1, wk = wv & 1;

  const int bid = (int)blockIdx.x;
  const int head = ((bid & 7) << 1) | ((bid >> 3) & 1);  // 2 heads per XCD
  const int L = bid >> 4;                                // 0..47
  int g, it0, itEnd;
  if (L < 16) { g = 16 + L; it0 = 0; itEnd = 16; }
  else {
    const int j = (L - 16) >> 1;
    if ((L & 1) == 0) { g = 15 - j; it0 = 0; itEnd = g + 1; }
    else             { g = 31 - j; it0 = 16; itEnd = g + 1; }
  }
  const size_t hoff = (size_t)head * 128;
  const int qw = g * 64 + wq * 32;
  _Float16* Pw = Pb + wv * (32 * 40);

  half8 qf[8];
  const _Float16 scl = (_Float16)0.08838834764831845f;
  #pragma unroll
  for (int ks = 0; ks < 8; ++ks) {
    half8 t = *(const half8*)(Qp + (size_t)(qw + l31) * 2048 + hoff + ks * 16 + hi * 8);
    #pragma unroll
    for (int j = 0; j < 8; ++j) t[j] = (_Float16)(t[j] * scl);
    qf[ks] = t;
  }

  auto stage = [&](int buf, int it) {
    const int kv0 = it * 64;
    #pragma unroll
    for (int i = 0; i < 4; ++i) {       // K: 4 rows per 1KB op
      const int rbase = wv * 16 + i * 4;
      const int row = rbase + (lane >> 4);
      const int gr = (lane & 15) ^ (row & 7);
      GLDS(Kp + (size_t)(kv0 + row) * 2048 + hoff + gr * 8,
           Ks + buf * 8192 + rbase * 128);
    }
    #pragma unroll
    for (int i = 0; i < 4; ++i) {       // V^T: 8 rows per 1KB op
      const int rbase = wv * 32 + i * 8;
      const int row = rbase + (lane >> 3);
      const int gr = (lane & 7) ^ (row & 7);
      GLDS(Vt + (size_t)(hoff + row) * 2048 + kv0 + gr * 8,
           Vs + buf * 8192 + rbase * 64);
    }
  };

  floatx16 o[4] = {};
  float rsum = 0.0f;

  stage(0, it0);
  asm volatile("s_waitcnt vmcnt(0)" ::: "memory");
  __builtin_amdgcn_s_barrier();

  int buf = 0;
  for (int it = it0; it < itEnd; ++it) {
    if (it + 1 < itEnd) stage(buf ^ 1, it + 1);
    const _Float16* Kb = Ks + buf * 8192;
    const _Float16* Vb = Vs + buf * 8192;

    const int krow = wk * 32 + l31;
    const int ksw = l31 & 7;
    floatx16 S = {};
    __builtin_amdgcn_s_setprio(1);
    #pragma unroll
    for (int ks = 0; ks < 8; ++ks) {
      half8 a = *(const half8*)(Kb + krow * 128 + (((ks * 2 + hi) ^ ksw) * 8));
      S = __builtin_amdgcn_mfma_f32_32x32x16_f16(a, qf[ks], S, 0, 0, 0);
    }
    __builtin_amdgcn_s_setprio(0);

    if (it == g) {
      const int kv0 = it * 64;
      const int qa = qw + l31;
      #pragma unroll
      for (int r = 0; r < 16; ++r) {
        const int ka = kv0 + wk * 32 + (r & 3) + 8 * (r >> 2) + 4 * hi;
        if (ka > qa) S[r] = -1e30f;
      }
    }

    #pragma unroll
    for (int r4 = 0; r4 < 4; ++r4) {
      float p0 = __expf(S[4 * r4 + 0] - 8.0f);
      float p1 = __expf(S[4 * r4 + 1] - 8.0f);
      float p2 = __expf(S[4 * r4 + 2] - 8.0f);
      float p3 = __expf(S[4 * r4 + 3] - 8.0f);
      rsum += (p0 + p1) + (p2 + p3);
      half4 pk;
      pk[0] = (_Float16)p0; pk[1] = (_Float16)p1;
      pk[2] = (_Float16)p2; pk[3] = (_Float16)p3;
      *(half4*)(Pw + l31 * 40 + r4 * 8 + hi * 4) = pk;
    }

    half8 pa0 = *(const half8*)(Pw + l31 * 40 + hi * 8);
    half8 pa1 = *(const half8*)(Pw + l31 * 40 + 16 + hi * 8);

    __builtin_amdgcn_s_setprio(1);
    #pragma unroll
    for (int dt = 0; dt < 4; ++dt) {
      const int vrow = dt * 32 + l31;
      const int vsw = vrow & 7;
      half8 b0 = *(const half8*)(Vb + vrow * 64 + (((wk * 4 + hi) ^ vsw) * 8));
      half8 b1 = *(const half8*)(Vb + vrow * 64 + (((wk * 4 + 2 + hi) ^ vsw) * 8));
      o[dt] = __builtin_amdgcn_mfma_f32_32x32x16_f16(pa0, b0, o[dt], 0, 0, 0);
      o[dt] = __builtin_amdgcn_mfma_f32_32x32x16_f16(pa1, b1, o[dt], 0, 0, 0);
    }
    __builtin_amdgcn_s_setprio(0);

    asm volatile("s_waitcnt vmcnt(0)" ::: "memory");
    __builtin_amdgcn_s_barrier();
    buf ^= 1;
  }

  float* Mo = (float*)smem;
  float* Mr = (float*)(smem + 16384);
  if (wk == 1) {
    #pragma unroll
    for (int dt = 0; dt < 4; ++dt)
      #pragma unroll
      for (int r = 0; r < 16; ++r)
        Mo[((wq * 4 + dt) * 16 + r) * 64 + lane] = o[dt][r];
    Mr[wq * 64 + lane] = rsum;
  }
  __syncthreads();
  if (wk == 0) {
    rsum += Mr[wq * 64 + lane];
    float rs = rsum;
    rs += __shfl_xor(rs, 32);
    if (hi == 0) Pr[(size_t)bid * 64 + wq * 32 + l31] = rs;
    #pragma unroll
    for (int dt = 0; dt < 4; ++dt)
      #pragma unroll
      for (int r = 0; r < 16; ++r) {
        const float w = o[dt][r] + Mo[((wq * 4 + dt) * 16 + r) * 64 + lane];
        const int ql = wq * 32 + (r & 3) + 8 * (r >> 2) + 4 * hi;
        Po[(size_t)bid * 8192 + ql * 128 + dt * 32 + l31] = (_Float16)w;
      }
  }
}

// ---------------------------------------------------------------- merge kv-chunk partials
__global__ __launch_bounds__(256) void attn_merge(const _Float16* __restrict__ Po,
                                                  const float* __restrict__ Pr,
                                                  _Float16* __restrict__ At) {
  const int bidx = (int)blockIdx.x;
  const int h = bidx & 15, g = bidx >> 4;
  const int hb = ((h & 1) << 3) | (h >> 1);
  const int L0 = (g >= 16) ? (g - 16) : (16 + 2 * (15 - g));
  const int U0 = L0 * 16 + hb;
  const bool two = (g >= 16);
  const int U1 = two ? ((17 + 2 * (31 - g)) * 16 + hb) : 0;
  const int t = threadIdx.x;
  const int q = t >> 2, cs = t & 3;
  const float r0 = Pr[(size_t)U0 * 64 + q];
  const float r1 = two ? Pr[(size_t)U1 * 64 + q] : 0.0f;
  const float inv = 1.0f / (r0 + r1);
  const size_t orow = (size_t)(g * 64 + q) * 2048 + h * 128;
  #pragma unroll
  for (int s = 0; s < 4; ++s) {
    const int d0 = (cs + s * 4) * 8;
    half8 a = *(const half8*)(Po + (size_t)U0 * 8192 + q * 128 + d0);
    half8 o;
    if (two) {
      half8 b = *(const half8*)(Po + (size_t)U1 * 8192 + q * 128 + d0);
      #pragma unroll
      for (int j = 0; j < 8; ++j) o[j] = (_Float16)(((float)a[j] + (float)b[j]) * inv);
    } else {
      #pragma unroll
      for (int j = 0; j < 8; ++j) o[j] = (_Float16)((float)a[j] * inv);
    }
    *(half8*)(At + orow + d0) = o;
  }
}

// ---------------------------------------------------------------- launch
extern "C" void kernel_launch(void* const* d_in, const int* in_sizes, int n_in,
                              void* d_out, int out_size, void* d_ws, size_t ws_size,
                              hipStream_t stream) {
  (void)in_sizes; (void)n_in; (void)out_size; (void)ws_size;
  const float* X  = (const float*)d_in[0];
  const float* Wq = (const float*)d_in[1];
  const float* Wk = (const float*)d_in[2];
  const float* Wv = (const float*)d_in[3];
  const float* Wo = (const float*)d_in[4];
  float* out = (float*)d_out;

  const size_t SZ = 2048ull * 2048ull;
  _Float16* ws  = (_Float16*)d_ws;
  _Float16* Xh  = ws + 0 * SZ;
  _Float16* Wqh = ws + 1 * SZ;   // Wq|Wk|Wv contiguous = one 6144x2048 matrix
  _Float16* Wkh = ws + 2 * SZ;
  _Float16* Wvh = ws + 3 * SZ;
  _Float16* Woh = ws + 4 * SZ;
  _Float16* Qp  = ws + 5 * SZ;   // Q|K|V contiguous = C of the fused GEMM
  _Float16* Kp  = ws + 6 * SZ;
  _Float16* Vp  = ws + 7 * SZ;
  _Float16* Vtg = Wqh;            // dead after QKV GEMM -> V^T
  _Float16* At  = Xh;             // dead after QKV GEMM -> attention output
  _Float16* Po  = Wkh;            // dead after QKV GEMM -> attn partials (spans Wkh+Wvh)
  float*    Pr  = (float*)Vp;     // dead after transpose -> chunk sum-exp

  const int n8 = (int)(SZ / 8);
  dim3 blk(256);

  cvt_f2h5<<<dim3(n8 / 256, 5), blk, 0, stream>>>(X, Wq, Wk, Wv, Wo,
                                                  Xh, Wqh, Wkh, Wvh, Woh, n8);

  // fused QKV projection: 256 blocks (1/CU), single-barrier K-tile, counted vmcnt
  gemm_qkv<<<dim3(32, 8), dim3(512), 147456, stream>>>(Xh, Wqh, Qp);

  // fused RoPE (Q,K) + V transpose
  rope_tr<<<8192 + 1024, blk, 0, stream>>>(Qp, Kp, Vp, Vtg);

  const size_t attn_lds = (4 * 64 * 128 + 4 * 32 * 40) * sizeof(_Float16);  // 75776 B
  attn_k<<<768, blk, attn_lds, stream>>>(Qp, Kp, Vtg, Po, Pr);
  attn_merge<<<512, blk, 0, stream>>>(Po, Pr, At);

  // O-projection: BK=32 triple-buffered, counted vmcnt, 3 blocks/CU
  gemm_o<<<dim3(16, 16), blk, 49152, stream>>>(At, Woh, out);
}